// Round 10
// baseline (699.960 us; speedup 1.0000x reference)
//
#include <hip/hip_runtime.h>

#define G 12
#define NC (G*G*G)

typedef __attribute__((ext_vector_type(8))) short bf16x8;
typedef __attribute__((ext_vector_type(4))) float f32x4;
typedef __attribute__((ext_vector_type(8))) short short8v;

__device__ __forceinline__ unsigned short f2bf(float f){
  union { float f; unsigned u; } v; v.f = f;
  unsigned u = v.u;
  u += 0x7FFFu + ((u >> 16) & 1u);
  return (unsigned short)(u >> 16);
}

__device__ __forceinline__ float bf2f(unsigned short h){
  union { unsigned u; float f; } v; v.u = ((unsigned)h) << 16;
  return v.f;
}

__device__ __forceinline__ void gl_lds16(const void* g, void* l){
  __builtin_amdgcn_global_load_lds((const __attribute__((address_space(1))) unsigned*)g,
                                   (__attribute__((address_space(3))) unsigned*)l, 16, 0, 0);
}

// lexicographic (d, idx) sorted top-3 insert: ties -> lower index (== jax top_k)
__device__ __forceinline__ void ins3L(float d, int s,
    float& m0, float& m1, float& m2, int& i0, int& i1, int& i2){
  bool c0 = (d < m0) || (d == m0 && s < i0);
  bool c1 = (d < m1) || (d == m1 && s < i1);
  bool c2 = (d < m2) || (d == m2 && s < i2);
  float n1d = c0 ? m0 : d;  int n1i = c0 ? i0 : s;
  float n2d = c1 ? m1 : d;  int n2i = c1 ? i1 : s;
  m0 = c0 ? d   : m0;  i0 = c0 ? s   : i0;
  m1 = c1 ? n1d : m1;  i1 = c1 ? n1i : i1;
  m2 = c2 ? n2d : m2;  i2 = c2 ? n2i : i2;
}

// ---- W fp32 -> bf16
__global__ __launch_bounds__(256) void k_convert_w(const float* __restrict__ W0, const float* __restrict__ W1,
                            unsigned short* __restrict__ W0b, unsigned short* __restrict__ W1b){
  int i = blockIdx.x*256 + threadIdx.x;
  if (i < 256*512) W0b[i] = f2bf(W0[i]);
  if (i < 256*256) W1b[i] = f2bf(W1[i]);
}

// ---- grid build: bbox -> histogram -> scan -> counting-sort scatter. 1 block/batch.
__global__ __launch_bounds__(1024) void k_build(const float* __restrict__ xyz2,
        float4* __restrict__ sp, int* __restrict__ sid,
        int* __restrict__ cst, float* __restrict__ box){
  int b = blockIdx.x, t = threadIdx.x;
  int lane = t & 63, wv = t >> 6;
  const float* px = xyz2 + (size_t)b*3*4096;
  // bbox
  float mnx=3.4e38f, mxx=-3.4e38f, mny=3.4e38f, mxy=-3.4e38f, mnz=3.4e38f, mxz=-3.4e38f;
  for (int i = t; i < 4096; i += 1024){
    float x = px[i], y = px[4096+i], z = px[8192+i];
    mnx=fminf(mnx,x); mxx=fmaxf(mxx,x);
    mny=fminf(mny,y); mxy=fmaxf(mxy,y);
    mnz=fminf(mnz,z); mxz=fmaxf(mxz,z);
  }
  #pragma unroll
  for (int d = 1; d < 64; d <<= 1){
    mnx=fminf(mnx,__shfl_xor(mnx,d)); mxx=fmaxf(mxx,__shfl_xor(mxx,d));
    mny=fminf(mny,__shfl_xor(mny,d)); mxy=fmaxf(mxy,__shfl_xor(mxy,d));
    mnz=fminf(mnz,__shfl_xor(mnz,d)); mxz=fmaxf(mxz,__shfl_xor(mxz,d));
  }
  __shared__ float rb[16][6];
  __shared__ float sbox[8];
  if (lane==0){ rb[wv][0]=mnx; rb[wv][1]=mxx; rb[wv][2]=mny; rb[wv][3]=mxy; rb[wv][4]=mnz; rb[wv][5]=mxz; }
  __syncthreads();
  if (t == 0){
    float a0=rb[0][0],a1=rb[0][1],a2=rb[0][2],a3=rb[0][3],a4=rb[0][4],a5=rb[0][5];
    for (int i=1;i<16;++i){
      a0=fminf(a0,rb[i][0]); a1=fmaxf(a1,rb[i][1]);
      a2=fminf(a2,rb[i][2]); a3=fmaxf(a3,rb[i][3]);
      a4=fminf(a4,rb[i][4]); a5=fmaxf(a5,rb[i][5]);
    }
    float hx = fmaxf((a1-a0)/G, 1e-6f), hy = fmaxf((a3-a2)/G, 1e-6f), hz = fmaxf((a5-a4)/G, 1e-6f);
    sbox[0]=a0; sbox[1]=a2; sbox[2]=a4; sbox[3]=hx; sbox[4]=hy; sbox[5]=hz;
    box[b*8+0]=a0; box[b*8+1]=a2; box[b*8+2]=a4;
    box[b*8+3]=hx; box[b*8+4]=hy; box[b*8+5]=hz;
  }
  __shared__ int cnt[NC];
  __shared__ int stt[NC+1];
  for (int i = t; i < NC; i += 1024) cnt[i] = 0;
  __syncthreads();
  float bmx=sbox[0], bmy=sbox[1], bmz=sbox[2];
  float ihx=1.0f/sbox[3], ihy=1.0f/sbox[4], ihz=1.0f/sbox[5];
  // histogram
  for (int i = t; i < 4096; i += 1024){
    float x = px[i], y = px[4096+i], z = px[8192+i];
    int cxi = min(G-1, max(0, (int)floorf((x-bmx)*ihx)));
    int cyi = min(G-1, max(0, (int)floorf((y-bmy)*ihy)));
    int czi = min(G-1, max(0, (int)floorf((z-bmz)*ihz)));
    atomicAdd(&cnt[(czi*G+cyi)*G+cxi], 1);
  }
  __syncthreads();
  // exclusive scan (each thread owns 2 cells)
  int c0 = 2*t, c1 = 2*t+1;
  int v0 = (c0 < NC) ? cnt[c0] : 0;
  int v1 = (c1 < NC) ? cnt[c1] : 0;
  int loc = v0 + v1;
  int incl = loc;
  #pragma unroll
  for (int d = 1; d < 64; d <<= 1){
    int up = __shfl_up(incl, d);
    if (lane >= d) incl += up;
  }
  __shared__ int wsum[16];
  __shared__ int wbase[16];
  if (lane == 63) wsum[wv] = incl;
  __syncthreads();
  if (t == 0){
    int acc = 0;
    for (int i=0;i<16;++i){ wbase[i]=acc; acc += wsum[i]; }
  }
  __syncthreads();
  int base = wbase[wv] + (incl - loc);
  if (c0 < NC) stt[c0] = base;
  if (c1 < NC) stt[c1] = base + v0;
  if (t == 0) stt[NC] = 4096;
  __syncthreads();
  if (c0 < NC) cnt[c0] = stt[c0];
  if (c1 < NC) cnt[c1] = stt[c1];
  __syncthreads();
  // scatter
  for (int i = t; i < 4096; i += 1024){
    float x = px[i], y = px[4096+i], z = px[8192+i];
    int cxi = min(G-1, max(0, (int)floorf((x-bmx)*ihx)));
    int cyi = min(G-1, max(0, (int)floorf((y-bmy)*ihy)));
    int czi = min(G-1, max(0, (int)floorf((z-bmz)*ihz)));
    int cid = (czi*G+cyi)*G+cxi;
    int pos = atomicAdd(&cnt[cid], 1);
    float r2 = x*x + y*y + z*z;
    float4 o; o.x=x; o.y=y; o.z=z; o.w=r2;
    sp[(size_t)b*4096 + pos] = o;
    sid[(size_t)b*4096 + pos] = i;
  }
  __syncthreads();
  for (int i = t; i <= NC; i += 1024) cst[(size_t)b*(NC+1) + i] = stt[i];
}

// ---- grid KNN: exact top-3 by expanding shells; writes final idx + weights
__global__ __launch_bounds__(256) void k_knn_grid(const float* __restrict__ xyz1,
        const float4* __restrict__ sp, const int* __restrict__ sid,
        const int* __restrict__ cst, const float* __restrict__ box,
        int* __restrict__ ki, float* __restrict__ kw){
  int qi = blockIdx.x*256 + threadIdx.x;
  int b = qi >> 14;
  int n = qi & 16383;
  const float* q = xyz1 + (size_t)b*3*16384;
  float qx = q[n], qy = q[16384+n], qz = q[32768+n];
  float r1 = qx*qx + qy*qy + qz*qz;
  const float* bx = box + b*8;
  float bmx=bx[0], bmy=bx[1], bmz=bx[2];
  float hx=bx[3], hy=bx[4], hz=bx[5];
  float ihx=1.0f/hx, ihy=1.0f/hy, ihz=1.0f/hz;
  int cx = min(G-1, max(0, (int)floorf((qx-bmx)*ihx)));
  int cy = min(G-1, max(0, (int)floorf((qy-bmy)*ihy)));
  int cz = min(G-1, max(0, (int)floorf((qz-bmz)*ihz)));
  const float4* P = sp + (size_t)b*4096;
  const int* I = sid + (size_t)b*4096;
  const int* CS = cst + (size_t)b*(NC+1);
  float m0=3.4e38f, m1=3.4e38f, m2=3.4e38f;
  int i0=0, i1=0, i2=0;

  auto scanRange = [&](int st, int en){
    for (int p = st; p < en; ++p){
      float4 c = P[p];
      float dot = qx*c.x + qy*c.y + qz*c.z;      // mul + fma + fma
      float d = (r1 + c.w) - 2.0f*dot;           // add + fma(-2)
      ins3L(d, I[p], m0, m1, m2, i0, i1, i2);
    }
  };

  for (int r = 0; r <= G; ++r){
    int zlo = max(cz-r,0), zhi = min(cz+r,G-1);
    int ylo = max(cy-r,0), yhi = min(cy+r,G-1);
    int xlo = max(cx-r,0), xhi = min(cx+r,G-1);
    for (int z = zlo; z <= zhi; ++z){
      bool zface = (z == cz-r) || (z == cz+r);
      for (int y = ylo; y <= yhi; ++y){
        bool yface = (y == cy-r) || (y == cy+r);
        int rowb = (z*G + y)*G;
        if (zface || yface){
          scanRange(CS[rowb + xlo], CS[rowb + xhi + 1]);
        } else {
          if (cx-r >= 0)  scanRange(CS[rowb + cx-r], CS[rowb + cx-r + 1]);
          if (cx+r <= G-1) scanRange(CS[rowb + cx+r], CS[rowb + cx+r + 1]);
        }
      }
    }
    // bound to any unexamined cell (outside cube radius r)
    float bnd = 1e30f;
    if (cx-r > 0)    bnd = fminf(bnd, qx - (bmx + (float)(cx-r)*hx));
    if (cx+r < G-1)  bnd = fminf(bnd, (bmx + (float)(cx+r+1)*hx) - qx);
    if (cy-r > 0)    bnd = fminf(bnd, qy - (bmy + (float)(cy-r)*hy));
    if (cy+r < G-1)  bnd = fminf(bnd, (bmy + (float)(cy+r+1)*hy) - qy);
    if (cz-r > 0)    bnd = fminf(bnd, qz - (bmz + (float)(cz-r)*hz));
    if (cz+r < G-1)  bnd = fminf(bnd, (bmz + (float)(cz+r+1)*hz) - qz);
    float bb = bnd - 1e-4f;                      // margin >> cell-plane fp slack
    if (bb > 0.f && bb*bb > m2) break;
  }
  float w0 = 1.0f/(m0+1e-8f), w1 = 1.0f/(m1+1e-8f), w2 = 1.0f/(m2+1e-8f);
  float inv = 1.0f/(w0+w1+w2);
  size_t kb = (size_t)qi*3;
  ki[kb]=i0; ki[kb+1]=i1; ki[kb+2]=i2;
  kw[kb]=w0*inv; kw[kb+1]=w1*inv; kw[kb+2]=w2*inv;
}

// ---- transpose points2 (B,256,S) -> f2t (B,S,256) fp32
__global__ __launch_bounds__(256) void k_tp2(const float* __restrict__ p2, float* __restrict__ f2t){
  __shared__ float tile[64][65];
  int bx = blockIdx.x;
  int by = blockIdx.y;
  int b  = blockIdx.z;
  int t = threadIdx.x; int tx = t & 63; int ty = t >> 6;
  const float* src = p2 + ((size_t)b*256 + by*64)*4096 + bx*64;
  #pragma unroll
  for (int i = 0; i < 16; ++i){
    int c = ty*16 + i;
    tile[c][tx] = src[(size_t)c*4096 + tx];
  }
  __syncthreads();
  float* dst = f2t + ((size_t)b*4096 + (size_t)bx*64)*256 + by*64;
  #pragma unroll
  for (int i = 0; i < 16; ++i){
    int s = ty*16 + i;
    dst[(size_t)s*256 + tx] = tile[tx][s];
  }
}

// ---- transpose points1 (B,256,N) -> Xt (B*N, 512) cols [0,256) bf16
__global__ __launch_bounds__(256) void k_tp1(const float* __restrict__ p1, unsigned short* __restrict__ Xt){
  __shared__ float tile[64][65];
  int bx = blockIdx.x;
  int by = blockIdx.y;
  int b  = blockIdx.z;
  int t = threadIdx.x; int tx = t & 63; int ty = t >> 6;
  const float* src = p1 + ((size_t)b*256 + by*64)*16384 + (size_t)bx*64;
  #pragma unroll
  for (int i = 0; i < 16; ++i){
    int c = ty*16 + i;
    tile[c][tx] = src[(size_t)c*16384 + tx];
  }
  __syncthreads();
  unsigned short* dst = Xt + ((size_t)b*16384 + (size_t)bx*64)*512 + by*64;
  #pragma unroll
  for (int i = 0; i < 16; ++i){
    int n = ty*16 + i;
    dst[(size_t)n*512 + tx] = f2bf(tile[tx][n]);
  }
}

// ---- interp -> Xt cols [256,512) bf16
__global__ __launch_bounds__(256) void k_interp(const float* __restrict__ f2t, const int* __restrict__ ki,
                         const float* __restrict__ kw, unsigned short* __restrict__ Xt){
  int t = threadIdx.x;
  int g = t >> 6; int lane = t & 63;
  size_t q = (size_t)blockIdx.x*4 + g;
  int b = (int)(q >> 14);
  const float* f2 = f2t + (size_t)b*4096*256;
  size_t kb = q*3;
  int i0 = ki[kb], i1 = ki[kb+1], i2 = ki[kb+2];
  float w0 = kw[kb], w1 = kw[kb+1], w2 = kw[kb+2];
  const float4 a = *(const float4*)(f2 + (size_t)i0*256 + lane*4);
  const float4 c = *(const float4*)(f2 + (size_t)i1*256 + lane*4);
  const float4 e = *(const float4*)(f2 + (size_t)i2*256 + lane*4);
  ushort4 o;
  o.x = f2bf(w0*a.x + w1*c.x + w2*e.x);
  o.y = f2bf(w0*a.y + w1*c.y + w2*e.y);
  o.z = f2bf(w0*a.z + w1*c.z + w2*e.z);
  o.w = f2bf(w0*a.w + w1*c.w + w2*e.w);
  *(ushort4*)(Xt + q*512 + 256 + lane*4) = o;
}

// ---- NT MFMA GEMM + fused BN-stat partials; bf16 output (gemm1)
template<int K>
__global__ __launch_bounds__(256) void k_gemm(const unsigned short* __restrict__ A,
                       const unsigned short* __restrict__ Bm,
                       unsigned short* __restrict__ Cb,
                       float* __restrict__ psum, float* __restrict__ psq){
  __shared__ unsigned short As[128*32];
  __shared__ unsigned short Bs[128*32];
  __shared__ float redS[2][128];
  __shared__ float redQ[2][128];
  int t = threadIdx.x;
  int bo = blockIdx.x * 128;
  size_t bn = (size_t)blockIdx.y * 128;
  int w = t >> 6, l = t & 63;
  int wr = w >> 1, wc = w & 1;
  f32x4 acc[4][4] = {};

  const char* Ap = (const char*)A;
  const char* Bp = (const char*)Bm;
  int r0 = t >> 2;
  int cb = (t & 3) * 16;
  for (int k0 = 0; k0 < K; k0 += 32){
    __syncthreads();
    #pragma unroll
    for (int p = 0; p < 2; ++p){
      int off = (t + p*256)*16;
      int r = r0 + p*64;
      gl_lds16(Ap + (size_t)(bo + r)*(K*2) + (size_t)k0*2 + cb, (char*)As + off);
      gl_lds16(Bp + (bn + r)*(K*2) + (size_t)k0*2 + cb, (char*)Bs + off);
    }
    __syncthreads();
    bf16x8 af[4], bfr[4];
    int lr = l & 15, lk = (l >> 4) * 8;
    #pragma unroll
    for (int mt = 0; mt < 4; ++mt)
      af[mt] = *(const bf16x8*)(As + (wr*64 + mt*16 + lr)*32 + lk);
    #pragma unroll
    for (int nt = 0; nt < 4; ++nt)
      bfr[nt] = *(const bf16x8*)(Bs + (wc*64 + nt*16 + lr)*32 + lk);
    #pragma unroll
    for (int mt = 0; mt < 4; ++mt)
      #pragma unroll
      for (int nt = 0; nt < 4; ++nt)
        acc[mt][nt] = __builtin_amdgcn_mfma_f32_16x16x32_bf16(af[mt], bfr[nt], acc[mt][nt], 0, 0, 0);
  }
  int lo = (l >> 4) * 4, ln = l & 15;
  #pragma unroll
  for (int mt = 0; mt < 4; ++mt){
    #pragma unroll
    for (int nt = 0; nt < 4; ++nt){
      size_t n = bn + wc*64 + nt*16 + ln;
      int o = bo + wr*64 + mt*16 + lo;
      ushort4 ov;
      ov.x = f2bf(acc[mt][nt][0]); ov.y = f2bf(acc[mt][nt][1]);
      ov.z = f2bf(acc[mt][nt][2]); ov.w = f2bf(acc[mt][nt][3]);
      *(ushort4*)(Cb + n*256 + o) = ov;
    }
  }
  float ps[16], pq[16];
  #pragma unroll
  for (int mt = 0; mt < 4; ++mt){
    #pragma unroll
    for (int j = 0; j < 4; ++j){
      float s = 0.f, qv = 0.f;
      #pragma unroll
      for (int nt = 0; nt < 4; ++nt){
        float v = acc[mt][nt][j];
        s += v; qv += v*v;
      }
      ps[mt*4+j] = s; pq[mt*4+j] = qv;
    }
  }
  #pragma unroll
  for (int dlt = 1; dlt < 16; dlt <<= 1){
    #pragma unroll
    for (int i = 0; i < 16; ++i){
      ps[i] += __shfl_xor(ps[i], dlt);
      pq[i] += __shfl_xor(pq[i], dlt);
    }
  }
  if ((l & 15) == 0){
    #pragma unroll
    for (int mt = 0; mt < 4; ++mt){
      #pragma unroll
      for (int j = 0; j < 4; ++j){
        int ol = wr*64 + mt*16 + (l>>4)*4 + j;
        redS[wc][ol] = ps[mt*4+j];
        redQ[wc][ol] = pq[mt*4+j];
      }
    }
  }
  __syncthreads();
  if (t < 128){
    psum[(size_t)(bo + t)*256 + blockIdx.y] = redS[0][t] + redS[1][t];
    psq [(size_t)(bo + t)*256 + blockIdx.y] = redQ[0][t] + redQ[1][t];
  }
}

// ---- gemm2 with fused BN-apply+ReLU on the B operand
__global__ __launch_bounds__(256) void k_gemm2(const unsigned short* __restrict__ A,
                       const unsigned short* __restrict__ C1,
                       const float* __restrict__ scale, const float* __restrict__ shift,
                       unsigned short* __restrict__ Cb,
                       float* __restrict__ psum, float* __restrict__ psq){
  const int K = 256;
  __shared__ unsigned short As[128*32];
  __shared__ unsigned short Bs[128*32];
  __shared__ float redS[2][128];
  __shared__ float redQ[2][128];
  int t = threadIdx.x;
  int bo = blockIdx.x * 128;
  size_t bn = (size_t)blockIdx.y * 128;
  int w = t >> 6, l = t & 63;
  int wr = w >> 1, wc = w & 1;
  f32x4 acc[4][4] = {};

  const char* Ap = (const char*)A;
  int r0 = t >> 2;
  int cb = (t & 3) * 16;
  int ce0 = (t & 3) * 8;
  for (int k0 = 0; k0 < K; k0 += 32){
    int ce = k0 + ce0;
    float4 a0 = *(const float4*)(scale+ce); float4 a1 = *(const float4*)(scale+ce+4);
    float4 b0 = *(const float4*)(shift+ce); float4 b1 = *(const float4*)(shift+ce+4);
    float sc[8] = {a0.x,a0.y,a0.z,a0.w,a1.x,a1.y,a1.z,a1.w};
    float sh[8] = {b0.x,b0.y,b0.z,b0.w,b1.x,b1.y,b1.z,b1.w};
    short8v vin[2];
    #pragma unroll
    for (int p = 0; p < 2; ++p){
      int r = r0 + p*64;
      vin[p] = *(const short8v*)(C1 + (bn + r)*256 + ce);
    }
    __syncthreads();
    #pragma unroll
    for (int p = 0; p < 2; ++p){
      int r = r0 + p*64;
      gl_lds16(Ap + (size_t)(bo + r)*(K*2) + (size_t)k0*2 + cb, (char*)As + (t + p*256)*16);
    }
    #pragma unroll
    for (int p = 0; p < 2; ++p){
      short8v pv;
      #pragma unroll
      for (int j = 0; j < 8; ++j){
        float y = fmaxf(0.f, bf2f((unsigned short)vin[p][j])*sc[j] + sh[j]);
        pv[j] = (short)f2bf(y);
      }
      *(short8v*)((char*)Bs + (t + p*256)*16) = pv;
    }
    __syncthreads();
    bf16x8 af[4], bfr[4];
    int lr = l & 15, lk = (l >> 4) * 8;
    #pragma unroll
    for (int mt = 0; mt < 4; ++mt)
      af[mt] = *(const bf16x8*)(As + (wr*64 + mt*16 + lr)*32 + lk);
    #pragma unroll
    for (int nt = 0; nt < 4; ++nt)
      bfr[nt] = *(const bf16x8*)(Bs + (wc*64 + nt*16 + lr)*32 + lk);
    #pragma unroll
    for (int mt = 0; mt < 4; ++mt)
      #pragma unroll
      for (int nt = 0; nt < 4; ++nt)
        acc[mt][nt] = __builtin_amdgcn_mfma_f32_16x16x32_bf16(af[mt], bfr[nt], acc[mt][nt], 0, 0, 0);
  }
  int lo = (l >> 4) * 4, ln = l & 15;
  #pragma unroll
  for (int mt = 0; mt < 4; ++mt){
    #pragma unroll
    for (int nt = 0; nt < 4; ++nt){
      size_t n = bn + wc*64 + nt*16 + ln;
      int o = bo + wr*64 + mt*16 + lo;
      ushort4 ov;
      ov.x = f2bf(acc[mt][nt][0]); ov.y = f2bf(acc[mt][nt][1]);
      ov.z = f2bf(acc[mt][nt][2]); ov.w = f2bf(acc[mt][nt][3]);
      *(ushort4*)(Cb + n*256 + o) = ov;
    }
  }
  float ps[16], pq[16];
  #pragma unroll
  for (int mt = 0; mt < 4; ++mt){
    #pragma unroll
    for (int j = 0; j < 4; ++j){
      float s = 0.f, qv = 0.f;
      #pragma unroll
      for (int nt = 0; nt < 4; ++nt){
        float v = acc[mt][nt][j];
        s += v; qv += v*v;
      }
      ps[mt*4+j] = s; pq[mt*4+j] = qv;
    }
  }
  #pragma unroll
  for (int dlt = 1; dlt < 16; dlt <<= 1){
    #pragma unroll
    for (int i = 0; i < 16; ++i){
      ps[i] += __shfl_xor(ps[i], dlt);
      pq[i] += __shfl_xor(pq[i], dlt);
    }
  }
  if ((l & 15) == 0){
    #pragma unroll
    for (int mt = 0; mt < 4; ++mt){
      #pragma unroll
      for (int j = 0; j < 4; ++j){
        int ol = wr*64 + mt*16 + (l>>4)*4 + j;
        redS[wc][ol] = ps[mt*4+j];
        redQ[wc][ol] = pq[mt*4+j];
      }
    }
  }
  __syncthreads();
  if (t < 128){
    psum[(size_t)(bo + t)*256 + blockIdx.y] = redS[0][t] + redS[1][t];
    psq [(size_t)(bo + t)*256 + blockIdx.y] = redQ[0][t] + redQ[1][t];
  }
}

// ---- finalize BN stats
__global__ __launch_bounds__(256) void k_stats_f(const float* __restrict__ psum, const float* __restrict__ psq,
                          const float* __restrict__ gamma, const float* __restrict__ beta,
                          float* __restrict__ scale, float* __restrict__ shift){
  int o = blockIdx.x; int t = threadIdx.x;
  float s = psum[(size_t)o*256 + t];
  float q = psq [(size_t)o*256 + t];
  #pragma unroll
  for (int d = 1; d < 64; d <<= 1){
    s += __shfl_xor(s, d);
    q += __shfl_xor(q, d);
  }
  __shared__ float ls[4], lq[4];
  if ((t & 63) == 0){ ls[t>>6] = s; lq[t>>6] = q; }
  __syncthreads();
  if (t == 0){
    float S = ls[0]+ls[1]+ls[2]+ls[3];
    float Q = lq[0]+lq[1]+lq[2]+lq[3];
    const float invc = 1.0f/32768.0f;
    float mean = S*invc;
    float var = Q*invc - mean*mean;
    float sc = gamma[o]*rsqrtf(var + 1e-5f);
    scale[o] = sc;
    shift[o] = beta[o] - mean*sc;
  }
}

// ---- BN apply + relu + transpose: bf16 C2 -> out (B,256,N) fp32
__global__ __launch_bounds__(256) void k_bn_out(const unsigned short* __restrict__ Cb, const float* __restrict__ scale,
                         const float* __restrict__ shift, float* __restrict__ out){
  __shared__ float tile[64][65];
  int bx = blockIdx.x;
  int by = blockIdx.y;
  int b  = blockIdx.z;
  int t = threadIdx.x; int tx = t & 63; int ty = t >> 6;
  const unsigned short* src = Cb + ((size_t)b*16384 + (size_t)bx*64)*256 + by*64;
  int o = by*64 + tx;
  float sc = scale[o], sh = shift[o];
  #pragma unroll
  for (int i = 0; i < 16; ++i){
    int n = ty*16 + i;
    float v = bf2f(src[(size_t)n*256 + tx]);
    tile[n][tx] = fmaxf(0.f, v*sc + sh);
  }
  __syncthreads();
  float* dst = out + ((size_t)b*256 + by*64)*16384 + (size_t)bx*64;
  #pragma unroll
  for (int i = 0; i < 16; ++i){
    int oo = ty*16 + i;
    dst[(size_t)oo*16384 + tx] = tile[tx][oo];
  }
}

extern "C" void kernel_launch(void* const* d_in, const int* in_sizes, int n_in,
                              void* d_out, int out_size, void* d_ws, size_t ws_size,
                              hipStream_t stream){
  const float* xyz1    = (const float*)d_in[0];
  const float* xyz2    = (const float*)d_in[1];
  const float* points1 = (const float*)d_in[2];
  const float* points2 = (const float*)d_in[3];
  const float* W0  = (const float*)d_in[4];
  const float* g0  = (const float*)d_in[6];
  const float* be0 = (const float*)d_in[7];
  const float* W1  = (const float*)d_in[8];
  const float* g1  = (const float*)d_in[10];
  const float* be1 = (const float*)d_in[11];

  char* w = (char*)d_ws;
  size_t o = 0;
  float* f2t = (float*)(w + o); o += 8388608;            // (B,S,256) fp32
  float4* sp = (float4*)(w + o); o += 131072;            // sorted pts
  int* sid   = (int*)(w + o);   o += 32768;              // sorted ids
  int* cst   = (int*)(w + o);   o += 16384;              // cell starts (2x1729)
  float* gbox= (float*)(w + o); o += 256;                // per-batch bbox
  int*   kidx= (int*)(w + o);   o += 393216;             // final idx
  float* kww = (float*)(w + o); o += 393216;             // final weights
  unsigned short* W0b = (unsigned short*)(w + o); o += 262144;
  unsigned short* W1b = (unsigned short*)(w + o); o += 131072;
  float* psum = (float*)(w + o); o += 262144;            // [256 o][256 nblk]
  float* psq  = (float*)(w + o); o += 262144;
  float* scale1 = (float*)(w + o); o += 1024;
  float* shift1 = (float*)(w + o); o += 1024;
  float* scale2 = (float*)(w + o); o += 1024;
  float* shift2 = (float*)(w + o); o += 1024;
  unsigned short* Xt = (unsigned short*)(w + o); size_t xto = o; o += 33554432;  // (32768,512) bf16
  unsigned short* C1b = (unsigned short*)(w + o); o += 16777216;   // (32768,256) bf16
  unsigned short* C2b = (unsigned short*)(w + xto);      // reuse Xt region

  k_build<<<2, 1024, 0, stream>>>(xyz2, sp, sid, cst, gbox);
  k_convert_w<<<512, 256, 0, stream>>>(W0, W1, W0b, W1b);
  k_tp2<<<dim3(64,4,2), 256, 0, stream>>>(points2, f2t);
  k_knn_grid<<<128, 256, 0, stream>>>(xyz1, sp, sid, cst, gbox, kidx, kww);
  k_tp1<<<dim3(256,4,2), 256, 0, stream>>>(points1, Xt);
  k_interp<<<8192, 256, 0, stream>>>(f2t, kidx, kww, Xt);
  k_gemm<512><<<dim3(2,256), 256, 0, stream>>>(W0b, Xt, C1b, psum, psq);
  k_stats_f<<<256, 256, 0, stream>>>(psum, psq, g0, be0, scale1, shift1);
  k_gemm2<<<dim3(2,256), 256, 0, stream>>>(W1b, C1b, scale1, shift1, C2b, psum, psq);
  k_stats_f<<<256, 256, 0, stream>>>(psum, psq, g1, be1, scale2, shift2);
  k_bn_out<<<dim3(256,4,2), 256, 0, stream>>>(C2b, scale2, shift2, (float*)d_out);
}

// Round 11
// 413.960 us; speedup vs baseline: 1.6909x; 1.6909x over previous
//
#include <hip/hip_runtime.h>

#define G 16
#define NC (G*G*G)

typedef __attribute__((ext_vector_type(8))) short bf16x8;
typedef __attribute__((ext_vector_type(4))) float f32x4;
typedef __attribute__((ext_vector_type(8))) short short8v;

__device__ __forceinline__ unsigned short f2bf(float f){
  union { float f; unsigned u; } v; v.f = f;
  unsigned u = v.u;
  u += 0x7FFFu + ((u >> 16) & 1u);
  return (unsigned short)(u >> 16);
}

__device__ __forceinline__ float bf2f(unsigned short h){
  union { unsigned u; float f; } v; v.u = ((unsigned)h) << 16;
  return v.f;
}

__device__ __forceinline__ void gl_lds16(const void* g, void* l){
  __builtin_amdgcn_global_load_lds((const __attribute__((address_space(1))) unsigned*)g,
                                   (__attribute__((address_space(3))) unsigned*)l, 16, 0, 0);
}

// lexicographic (d, idx) sorted top-3 insert: ties -> lower index (== jax top_k),
// order-independent => safe under any scan schedule. (R10-verified)
__device__ __forceinline__ void ins3L(float d, int s,
    float& m0, float& m1, float& m2, int& i0, int& i1, int& i2){
  bool c0 = (d < m0) || (d == m0 && s < i0);
  bool c1 = (d < m1) || (d == m1 && s < i1);
  bool c2 = (d < m2) || (d == m2 && s < i2);
  float n1d = c0 ? m0 : d;  int n1i = c0 ? i0 : s;
  float n2d = c1 ? m1 : d;  int n2i = c1 ? i1 : s;
  m0 = c0 ? d   : m0;  i0 = c0 ? s   : i0;
  m1 = c1 ? n1d : m1;  i1 = c1 ? n1i : i1;
  m2 = c2 ? n2d : m2;  i2 = c2 ? n2i : i2;
}

// ---- W fp32 -> bf16
__global__ __launch_bounds__(256) void k_convert_w(const float* __restrict__ W0, const float* __restrict__ W1,
                            unsigned short* __restrict__ W0b, unsigned short* __restrict__ W1b){
  int i = blockIdx.x*256 + threadIdx.x;
  if (i < 256*512) W0b[i] = f2bf(W0[i]);
  if (i < 256*256) W1b[i] = f2bf(W1[i]);
}

// ---- grid build for points: bbox -> histogram -> scan -> counting-sort. 1 block/batch.
__global__ __launch_bounds__(1024) void k_build(const float* __restrict__ xyz2,
        float4* __restrict__ sp, int* __restrict__ sid,
        int* __restrict__ cst, float* __restrict__ box){
  int b = blockIdx.x, t = threadIdx.x;
  int lane = t & 63, wv = t >> 6;
  const float* px = xyz2 + (size_t)b*3*4096;
  float mnx=3.4e38f, mxx=-3.4e38f, mny=3.4e38f, mxy=-3.4e38f, mnz=3.4e38f, mxz=-3.4e38f;
  for (int i = t; i < 4096; i += 1024){
    float x = px[i], y = px[4096+i], z = px[8192+i];
    mnx=fminf(mnx,x); mxx=fmaxf(mxx,x);
    mny=fminf(mny,y); mxy=fmaxf(mxy,y);
    mnz=fminf(mnz,z); mxz=fmaxf(mxz,z);
  }
  #pragma unroll
  for (int d = 1; d < 64; d <<= 1){
    mnx=fminf(mnx,__shfl_xor(mnx,d)); mxx=fmaxf(mxx,__shfl_xor(mxx,d));
    mny=fminf(mny,__shfl_xor(mny,d)); mxy=fmaxf(mxy,__shfl_xor(mxy,d));
    mnz=fminf(mnz,__shfl_xor(mnz,d)); mxz=fmaxf(mxz,__shfl_xor(mxz,d));
  }
  __shared__ float rb[16][6];
  __shared__ float sbox[8];
  if (lane==0){ rb[wv][0]=mnx; rb[wv][1]=mxx; rb[wv][2]=mny; rb[wv][3]=mxy; rb[wv][4]=mnz; rb[wv][5]=mxz; }
  __syncthreads();
  if (t == 0){
    float a0=rb[0][0],a1=rb[0][1],a2=rb[0][2],a3=rb[0][3],a4=rb[0][4],a5=rb[0][5];
    for (int i=1;i<16;++i){
      a0=fminf(a0,rb[i][0]); a1=fmaxf(a1,rb[i][1]);
      a2=fminf(a2,rb[i][2]); a3=fmaxf(a3,rb[i][3]);
      a4=fminf(a4,rb[i][4]); a5=fmaxf(a5,rb[i][5]);
    }
    float hx = fmaxf((a1-a0)/G, 1e-6f), hy = fmaxf((a3-a2)/G, 1e-6f), hz = fmaxf((a5-a4)/G, 1e-6f);
    sbox[0]=a0; sbox[1]=a2; sbox[2]=a4; sbox[3]=hx; sbox[4]=hy; sbox[5]=hz;
    box[b*8+0]=a0; box[b*8+1]=a2; box[b*8+2]=a4;
    box[b*8+3]=hx; box[b*8+4]=hy; box[b*8+5]=hz;
  }
  __shared__ int cnt[NC];
  __shared__ int stt[NC+1];
  for (int i = t; i < NC; i += 1024) cnt[i] = 0;
  __syncthreads();
  float bmx=sbox[0], bmy=sbox[1], bmz=sbox[2];
  float ihx=1.0f/sbox[3], ihy=1.0f/sbox[4], ihz=1.0f/sbox[5];
  for (int i = t; i < 4096; i += 1024){
    float x = px[i], y = px[4096+i], z = px[8192+i];
    int cxi = min(G-1, max(0, (int)floorf((x-bmx)*ihx)));
    int cyi = min(G-1, max(0, (int)floorf((y-bmy)*ihy)));
    int czi = min(G-1, max(0, (int)floorf((z-bmz)*ihz)));
    atomicAdd(&cnt[(czi*G+cyi)*G+cxi], 1);
  }
  __syncthreads();
  // exclusive scan: 4 cells per thread (NC = 4096 = 1024*4)
  int v0 = cnt[4*t], v1 = cnt[4*t+1], v2 = cnt[4*t+2], v3 = cnt[4*t+3];
  int loc = v0+v1+v2+v3;
  int incl = loc;
  #pragma unroll
  for (int d = 1; d < 64; d <<= 1){
    int up = __shfl_up(incl, d);
    if (lane >= d) incl += up;
  }
  __shared__ int wsum[16];
  __shared__ int wbase[16];
  if (lane == 63) wsum[wv] = incl;
  __syncthreads();
  if (t == 0){
    int acc = 0;
    for (int i=0;i<16;++i){ wbase[i]=acc; acc += wsum[i]; }
  }
  __syncthreads();
  int run = wbase[wv] + (incl - loc);
  stt[4*t] = run; run += v0;
  stt[4*t+1] = run; run += v1;
  stt[4*t+2] = run; run += v2;
  stt[4*t+3] = run;
  if (t == 0) stt[NC] = 4096;
  __syncthreads();
  cnt[4*t]=stt[4*t]; cnt[4*t+1]=stt[4*t+1]; cnt[4*t+2]=stt[4*t+2]; cnt[4*t+3]=stt[4*t+3];
  __syncthreads();
  for (int i = t; i < 4096; i += 1024){
    float x = px[i], y = px[4096+i], z = px[8192+i];
    int cxi = min(G-1, max(0, (int)floorf((x-bmx)*ihx)));
    int cyi = min(G-1, max(0, (int)floorf((y-bmy)*ihy)));
    int czi = min(G-1, max(0, (int)floorf((z-bmz)*ihz)));
    int cid = (czi*G+cyi)*G+cxi;
    int pos = atomicAdd(&cnt[cid], 1);
    float r2 = x*x + y*y + z*z;
    float4 o; o.x=x; o.y=y; o.z=z; o.w=r2;
    sp[(size_t)b*4096 + pos] = o;
    sid[(size_t)b*4096 + pos] = i;
  }
  __syncthreads();
  for (int i = t; i <= NC; i += 1024) cst[(size_t)b*(NC+1) + i] = stt[i];
}

// ---- bin queries into the same grid: counting sort -> qorder, qcst. 1 block/batch.
__global__ __launch_bounds__(1024) void k_qbin(const float* __restrict__ xyz1, const float* __restrict__ box,
        int* __restrict__ qorder, int* __restrict__ qcst){
  int b = blockIdx.x, t = threadIdx.x;
  int lane = t & 63, wv = t >> 6;
  const float* q = xyz1 + (size_t)b*3*16384;
  const float* bx = box + b*8;
  float bmx=bx[0], bmy=bx[1], bmz=bx[2];
  float ihx=1.0f/bx[3], ihy=1.0f/bx[4], ihz=1.0f/bx[5];
  __shared__ int cnt[NC];
  __shared__ int stt[NC+1];
  for (int i = t; i < NC; i += 1024) cnt[i] = 0;
  __syncthreads();
  for (int i = t; i < 16384; i += 1024){
    float x = q[i], y = q[16384+i], z = q[32768+i];
    int cxi = min(G-1, max(0, (int)floorf((x-bmx)*ihx)));
    int cyi = min(G-1, max(0, (int)floorf((y-bmy)*ihy)));
    int czi = min(G-1, max(0, (int)floorf((z-bmz)*ihz)));
    atomicAdd(&cnt[(czi*G+cyi)*G+cxi], 1);
  }
  __syncthreads();
  int v0 = cnt[4*t], v1 = cnt[4*t+1], v2 = cnt[4*t+2], v3 = cnt[4*t+3];
  int loc = v0+v1+v2+v3;
  int incl = loc;
  #pragma unroll
  for (int d = 1; d < 64; d <<= 1){
    int up = __shfl_up(incl, d);
    if (lane >= d) incl += up;
  }
  __shared__ int wsum[16];
  __shared__ int wbase[16];
  if (lane == 63) wsum[wv] = incl;
  __syncthreads();
  if (t == 0){
    int acc = 0;
    for (int i=0;i<16;++i){ wbase[i]=acc; acc += wsum[i]; }
  }
  __syncthreads();
  int run = wbase[wv] + (incl - loc);
  stt[4*t] = run; run += v0;
  stt[4*t+1] = run; run += v1;
  stt[4*t+2] = run; run += v2;
  stt[4*t+3] = run;
  if (t == 0) stt[NC] = 16384;
  __syncthreads();
  cnt[4*t]=stt[4*t]; cnt[4*t+1]=stt[4*t+1]; cnt[4*t+2]=stt[4*t+2]; cnt[4*t+3]=stt[4*t+3];
  __syncthreads();
  for (int i = t; i < 16384; i += 1024){
    float x = q[i], y = q[16384+i], z = q[32768+i];
    int cxi = min(G-1, max(0, (int)floorf((x-bmx)*ihx)));
    int cyi = min(G-1, max(0, (int)floorf((y-bmy)*ihy)));
    int czi = min(G-1, max(0, (int)floorf((z-bmz)*ihz)));
    int cid = (czi*G+cyi)*G+cxi;
    int pos = atomicAdd(&cnt[cid], 1);
    qorder[(size_t)b*16384 + pos] = i;
  }
  __syncthreads();
  for (int i = t; i <= NC; i += 1024) qcst[(size_t)b*(NC+1) + i] = stt[i];
}

// ---- wave-per-cell grid KNN: scalar candidate ranges, 64 queries/wave in lockstep
__global__ __launch_bounds__(256) void k_knn_gc(const float* __restrict__ xyz1,
        const float4* __restrict__ sp, const int* __restrict__ sid,
        const int* __restrict__ cst, const float* __restrict__ box,
        const int* __restrict__ qorder, const int* __restrict__ qcst,
        int* __restrict__ ki, float* __restrict__ kw){
  int lane = threadIdx.x & 63;
  int wid = blockIdx.x*4 + (threadIdx.x >> 6);          // 8192 waves
  int b    = __builtin_amdgcn_readfirstlane(wid >> 12);
  int cell = __builtin_amdgcn_readfirstlane(wid & (NC-1));
  const int* QC = qcst + (size_t)b*(NC+1);
  int qs = QC[cell], qe = QC[cell+1];
  if (qs >= qe) return;
  int cx = cell & (G-1), cy = (cell >> 4) & (G-1), cz = cell >> 8;
  const float* bx = box + b*8;
  float bmx=bx[0], bmy=bx[1], bmz=bx[2];
  float hx=bx[3], hy=bx[4], hz=bx[5];
  const float4* P = sp + (size_t)b*4096;
  const int* I = sid + (size_t)b*4096;
  const int* CS = cst + (size_t)b*(NC+1);
  const float* q = xyz1 + (size_t)b*3*16384;
  const int* QO = qorder + (size_t)b*16384;

  for (int base = qs; base < qe; base += 64){
    int idx = base + lane;
    bool act = idx < qe;
    int qn = QO[act ? idx : qs];
    float qx = q[qn], qy = q[16384+qn], qz = q[32768+qn];
    float r1 = qx*qx + qy*qy + qz*qz;
    float m0=3.4e38f, m1=3.4e38f, m2=3.4e38f;
    int i0=0, i1=0, i2=0;

    auto scanRange = [&](int st, int en){
      for (int p = st; p < en; ++p){
        float4 c = P[p];
        float dot = qx*c.x + qy*c.y + qz*c.z;      // mul + fma + fma
        float d = (r1 + c.w) - 2.0f*dot;           // add + fma(-2)
        ins3L(d, I[p], m0, m1, m2, i0, i1, i2);
      }
    };

    for (int r = 0; r <= G; ++r){
      int zlo = max(cz-r,0), zhi = min(cz+r,G-1);
      int ylo = max(cy-r,0), yhi = min(cy+r,G-1);
      int xlo = max(cx-r,0), xhi = min(cx+r,G-1);
      for (int z = zlo; z <= zhi; ++z){
        bool zface = (z == cz-r) || (z == cz+r);
        for (int y = ylo; y <= yhi; ++y){
          bool yface = (y == cy-r) || (y == cy+r);
          int rowb = (z*G + y)*G;
          if (zface || yface){
            scanRange(CS[rowb + xlo], CS[rowb + xhi + 1]);
          } else {
            if (cx-r >= 0)   scanRange(CS[rowb + cx-r], CS[rowb + cx-r + 1]);
            if (cx+r <= G-1) scanRange(CS[rowb + cx+r], CS[rowb + cx+r + 1]);
          }
        }
      }
      float bnd = 1e30f;
      if (cx-r > 0)    bnd = fminf(bnd, qx - (bmx + (float)(cx-r)*hx));
      if (cx+r < G-1)  bnd = fminf(bnd, (bmx + (float)(cx+r+1)*hx) - qx);
      if (cy-r > 0)    bnd = fminf(bnd, qy - (bmy + (float)(cy-r)*hy));
      if (cy+r < G-1)  bnd = fminf(bnd, (bmy + (float)(cy+r+1)*hy) - qy);
      if (cz-r > 0)    bnd = fminf(bnd, qz - (bmz + (float)(cz-r)*hz));
      if (cz+r < G-1)  bnd = fminf(bnd, (bmz + (float)(cz+r+1)*hz) - qz);
      float bb = bnd - 1e-4f;                      // margin >> cell-plane fp slack
      bool done = (bb > 0.f) && (bb*bb > m2);
      if (__all(done)) break;                       // extra shells for stragglers are no-ops (bound proof)
    }
    if (act){
      float w0 = 1.0f/(m0+1e-8f), w1 = 1.0f/(m1+1e-8f), w2 = 1.0f/(m2+1e-8f);
      float inv = 1.0f/(w0+w1+w2);
      size_t kb = ((size_t)b*16384 + qn)*3;
      ki[kb]=i0; ki[kb+1]=i1; ki[kb+2]=i2;
      kw[kb]=w0*inv; kw[kb+1]=w1*inv; kw[kb+2]=w2*inv;
    }
  }
}

// ---- transpose points2 (B,256,S) -> f2t (B,S,256) fp32
__global__ __launch_bounds__(256) void k_tp2(const float* __restrict__ p2, float* __restrict__ f2t){
  __shared__ float tile[64][65];
  int bx = blockIdx.x;
  int by = blockIdx.y;
  int b  = blockIdx.z;
  int t = threadIdx.x; int tx = t & 63; int ty = t >> 6;
  const float* src = p2 + ((size_t)b*256 + by*64)*4096 + bx*64;
  #pragma unroll
  for (int i = 0; i < 16; ++i){
    int c = ty*16 + i;
    tile[c][tx] = src[(size_t)c*4096 + tx];
  }
  __syncthreads();
  float* dst = f2t + ((size_t)b*4096 + (size_t)bx*64)*256 + by*64;
  #pragma unroll
  for (int i = 0; i < 16; ++i){
    int s = ty*16 + i;
    dst[(size_t)s*256 + tx] = tile[tx][s];
  }
}

// ---- transpose points1 (B,256,N) -> Xt (B*N, 512) cols [0,256) bf16
__global__ __launch_bounds__(256) void k_tp1(const float* __restrict__ p1, unsigned short* __restrict__ Xt){
  __shared__ float tile[64][65];
  int bx = blockIdx.x;
  int by = blockIdx.y;
  int b  = blockIdx.z;
  int t = threadIdx.x; int tx = t & 63; int ty = t >> 6;
  const float* src = p1 + ((size_t)b*256 + by*64)*16384 + (size_t)bx*64;
  #pragma unroll
  for (int i = 0; i < 16; ++i){
    int c = ty*16 + i;
    tile[c][tx] = src[(size_t)c*16384 + tx];
  }
  __syncthreads();
  unsigned short* dst = Xt + ((size_t)b*16384 + (size_t)bx*64)*512 + by*64;
  #pragma unroll
  for (int i = 0; i < 16; ++i){
    int n = ty*16 + i;
    dst[(size_t)n*512 + tx] = f2bf(tile[tx][n]);
  }
}

// ---- interp -> Xt cols [256,512) bf16
__global__ __launch_bounds__(256) void k_interp(const float* __restrict__ f2t, const int* __restrict__ ki,
                         const float* __restrict__ kw, unsigned short* __restrict__ Xt){
  int t = threadIdx.x;
  int g = t >> 6; int lane = t & 63;
  size_t q = (size_t)blockIdx.x*4 + g;
  int b = (int)(q >> 14);
  const float* f2 = f2t + (size_t)b*4096*256;
  size_t kb = q*3;
  int i0 = ki[kb], i1 = ki[kb+1], i2 = ki[kb+2];
  float w0 = kw[kb], w1 = kw[kb+1], w2 = kw[kb+2];
  const float4 a = *(const float4*)(f2 + (size_t)i0*256 + lane*4);
  const float4 c = *(const float4*)(f2 + (size_t)i1*256 + lane*4);
  const float4 e = *(const float4*)(f2 + (size_t)i2*256 + lane*4);
  ushort4 o;
  o.x = f2bf(w0*a.x + w1*c.x + w2*e.x);
  o.y = f2bf(w0*a.y + w1*c.y + w2*e.y);
  o.z = f2bf(w0*a.z + w1*c.z + w2*e.z);
  o.w = f2bf(w0*a.w + w1*c.w + w2*e.w);
  *(ushort4*)(Xt + q*512 + 256 + lane*4) = o;
}

// ---- NT MFMA GEMM + fused BN-stat partials; bf16 output (gemm1)
template<int K>
__global__ __launch_bounds__(256) void k_gemm(const unsigned short* __restrict__ A,
                       const unsigned short* __restrict__ Bm,
                       unsigned short* __restrict__ Cb,
                       float* __restrict__ psum, float* __restrict__ psq){
  __shared__ unsigned short As[128*32];
  __shared__ unsigned short Bs[128*32];
  __shared__ float redS[2][128];
  __shared__ float redQ[2][128];
  int t = threadIdx.x;
  int bo = blockIdx.x * 128;
  size_t bn = (size_t)blockIdx.y * 128;
  int w = t >> 6, l = t & 63;
  int wr = w >> 1, wc = w & 1;
  f32x4 acc[4][4] = {};

  const char* Ap = (const char*)A;
  const char* Bp = (const char*)Bm;
  int r0 = t >> 2;
  int cb = (t & 3) * 16;
  for (int k0 = 0; k0 < K; k0 += 32){
    __syncthreads();
    #pragma unroll
    for (int p = 0; p < 2; ++p){
      int off = (t + p*256)*16;
      int r = r0 + p*64;
      gl_lds16(Ap + (size_t)(bo + r)*(K*2) + (size_t)k0*2 + cb, (char*)As + off);
      gl_lds16(Bp + (bn + r)*(K*2) + (size_t)k0*2 + cb, (char*)Bs + off);
    }
    __syncthreads();
    bf16x8 af[4], bfr[4];
    int lr = l & 15, lk = (l >> 4) * 8;
    #pragma unroll
    for (int mt = 0; mt < 4; ++mt)
      af[mt] = *(const bf16x8*)(As + (wr*64 + mt*16 + lr)*32 + lk);
    #pragma unroll
    for (int nt = 0; nt < 4; ++nt)
      bfr[nt] = *(const bf16x8*)(Bs + (wc*64 + nt*16 + lr)*32 + lk);
    #pragma unroll
    for (int mt = 0; mt < 4; ++mt)
      #pragma unroll
      for (int nt = 0; nt < 4; ++nt)
        acc[mt][nt] = __builtin_amdgcn_mfma_f32_16x16x32_bf16(af[mt], bfr[nt], acc[mt][nt], 0, 0, 0);
  }
  int lo = (l >> 4) * 4, ln = l & 15;
  #pragma unroll
  for (int mt = 0; mt < 4; ++mt){
    #pragma unroll
    for (int nt = 0; nt < 4; ++nt){
      size_t n = bn + wc*64 + nt*16 + ln;
      int o = bo + wr*64 + mt*16 + lo;
      ushort4 ov;
      ov.x = f2bf(acc[mt][nt][0]); ov.y = f2bf(acc[mt][nt][1]);
      ov.z = f2bf(acc[mt][nt][2]); ov.w = f2bf(acc[mt][nt][3]);
      *(ushort4*)(Cb + n*256 + o) = ov;
    }
  }
  float ps[16], pq[16];
  #pragma unroll
  for (int mt = 0; mt < 4; ++mt){
    #pragma unroll
    for (int j = 0; j < 4; ++j){
      float s = 0.f, qv = 0.f;
      #pragma unroll
      for (int nt = 0; nt < 4; ++nt){
        float v = acc[mt][nt][j];
        s += v; qv += v*v;
      }
      ps[mt*4+j] = s; pq[mt*4+j] = qv;
    }
  }
  #pragma unroll
  for (int dlt = 1; dlt < 16; dlt <<= 1){
    #pragma unroll
    for (int i = 0; i < 16; ++i){
      ps[i] += __shfl_xor(ps[i], dlt);
      pq[i] += __shfl_xor(pq[i], dlt);
    }
  }
  if ((l & 15) == 0){
    #pragma unroll
    for (int mt = 0; mt < 4; ++mt){
      #pragma unroll
      for (int j = 0; j < 4; ++j){
        int ol = wr*64 + mt*16 + (l>>4)*4 + j;
        redS[wc][ol] = ps[mt*4+j];
        redQ[wc][ol] = pq[mt*4+j];
      }
    }
  }
  __syncthreads();
  if (t < 128){
    psum[(size_t)(bo + t)*256 + blockIdx.y] = redS[0][t] + redS[1][t];
    psq [(size_t)(bo + t)*256 + blockIdx.y] = redQ[0][t] + redQ[1][t];
  }
}

// ---- gemm2 with fused BN-apply+ReLU on the B operand
__global__ __launch_bounds__(256) void k_gemm2(const unsigned short* __restrict__ A,
                       const unsigned short* __restrict__ C1,
                       const float* __restrict__ scale, const float* __restrict__ shift,
                       unsigned short* __restrict__ Cb,
                       float* __restrict__ psum, float* __restrict__ psq){
  const int K = 256;
  __shared__ unsigned short As[128*32];
  __shared__ unsigned short Bs[128*32];
  __shared__ float redS[2][128];
  __shared__ float redQ[2][128];
  int t = threadIdx.x;
  int bo = blockIdx.x * 128;
  size_t bn = (size_t)blockIdx.y * 128;
  int w = t >> 6, l = t & 63;
  int wr = w >> 1, wc = w & 1;
  f32x4 acc[4][4] = {};

  const char* Ap = (const char*)A;
  int r0 = t >> 2;
  int cb = (t & 3) * 16;
  int ce0 = (t & 3) * 8;
  for (int k0 = 0; k0 < K; k0 += 32){
    int ce = k0 + ce0;
    float4 a0 = *(const float4*)(scale+ce); float4 a1 = *(const float4*)(scale+ce+4);
    float4 b0 = *(const float4*)(shift+ce); float4 b1 = *(const float4*)(shift+ce+4);
    float sc[8] = {a0.x,a0.y,a0.z,a0.w,a1.x,a1.y,a1.z,a1.w};
    float sh[8] = {b0.x,b0.y,b0.z,b0.w,b1.x,b1.y,b1.z,b1.w};
    short8v vin[2];
    #pragma unroll
    for (int p = 0; p < 2; ++p){
      int r = r0 + p*64;
      vin[p] = *(const short8v*)(C1 + (bn + r)*256 + ce);
    }
    __syncthreads();
    #pragma unroll
    for (int p = 0; p < 2; ++p){
      int r = r0 + p*64;
      gl_lds16(Ap + (size_t)(bo + r)*(K*2) + (size_t)k0*2 + cb, (char*)As + (t + p*256)*16);
    }
    #pragma unroll
    for (int p = 0; p < 2; ++p){
      short8v pv;
      #pragma unroll
      for (int j = 0; j < 8; ++j){
        float y = fmaxf(0.f, bf2f((unsigned short)vin[p][j])*sc[j] + sh[j]);
        pv[j] = (short)f2bf(y);
      }
      *(short8v*)((char*)Bs + (t + p*256)*16) = pv;
    }
    __syncthreads();
    bf16x8 af[4], bfr[4];
    int lr = l & 15, lk = (l >> 4) * 8;
    #pragma unroll
    for (int mt = 0; mt < 4; ++mt)
      af[mt] = *(const bf16x8*)(As + (wr*64 + mt*16 + lr)*32 + lk);
    #pragma unroll
    for (int nt = 0; nt < 4; ++nt)
      bfr[nt] = *(const bf16x8*)(Bs + (wc*64 + nt*16 + lr)*32 + lk);
    #pragma unroll
    for (int mt = 0; mt < 4; ++mt)
      #pragma unroll
      for (int nt = 0; nt < 4; ++nt)
        acc[mt][nt] = __builtin_amdgcn_mfma_f32_16x16x32_bf16(af[mt], bfr[nt], acc[mt][nt], 0, 0, 0);
  }
  int lo = (l >> 4) * 4, ln = l & 15;
  #pragma unroll
  for (int mt = 0; mt < 4; ++mt){
    #pragma unroll
    for (int nt = 0; nt < 4; ++nt){
      size_t n = bn + wc*64 + nt*16 + ln;
      int o = bo + wr*64 + mt*16 + lo;
      ushort4 ov;
      ov.x = f2bf(acc[mt][nt][0]); ov.y = f2bf(acc[mt][nt][1]);
      ov.z = f2bf(acc[mt][nt][2]); ov.w = f2bf(acc[mt][nt][3]);
      *(ushort4*)(Cb + n*256 + o) = ov;
    }
  }
  float ps[16], pq[16];
  #pragma unroll
  for (int mt = 0; mt < 4; ++mt){
    #pragma unroll
    for (int j = 0; j < 4; ++j){
      float s = 0.f, qv = 0.f;
      #pragma unroll
      for (int nt = 0; nt < 4; ++nt){
        float v = acc[mt][nt][j];
        s += v; qv += v*v;
      }
      ps[mt*4+j] = s; pq[mt*4+j] = qv;
    }
  }
  #pragma unroll
  for (int dlt = 1; dlt < 16; dlt <<= 1){
    #pragma unroll
    for (int i = 0; i < 16; ++i){
      ps[i] += __shfl_xor(ps[i], dlt);
      pq[i] += __shfl_xor(pq[i], dlt);
    }
  }
  if ((l & 15) == 0){
    #pragma unroll
    for (int mt = 0; mt < 4; ++mt){
      #pragma unroll
      for (int j = 0; j < 4; ++j){
        int ol = wr*64 + mt*16 + (l>>4)*4 + j;
        redS[wc][ol] = ps[mt*4+j];
        redQ[wc][ol] = pq[mt*4+j];
      }
    }
  }
  __syncthreads();
  if (t < 128){
    psum[(size_t)(bo + t)*256 + blockIdx.y] = redS[0][t] + redS[1][t];
    psq [(size_t)(bo + t)*256 + blockIdx.y] = redQ[0][t] + redQ[1][t];
  }
}

// ---- finalize BN stats
__global__ __launch_bounds__(256) void k_stats_f(const float* __restrict__ psum, const float* __restrict__ psq,
                          const float* __restrict__ gamma, const float* __restrict__ beta,
                          float* __restrict__ scale, float* __restrict__ shift){
  int o = blockIdx.x; int t = threadIdx.x;
  float s = psum[(size_t)o*256 + t];
  float q = psq [(size_t)o*256 + t];
  #pragma unroll
  for (int d = 1; d < 64; d <<= 1){
    s += __shfl_xor(s, d);
    q += __shfl_xor(q, d);
  }
  __shared__ float ls[4], lq[4];
  if ((t & 63) == 0){ ls[t>>6] = s; lq[t>>6] = q; }
  __syncthreads();
  if (t == 0){
    float S = ls[0]+ls[1]+ls[2]+ls[3];
    float Q = lq[0]+lq[1]+lq[2]+lq[3];
    const float invc = 1.0f/32768.0f;
    float mean = S*invc;
    float var = Q*invc - mean*mean;
    float sc = gamma[o]*rsqrtf(var + 1e-5f);
    scale[o] = sc;
    shift[o] = beta[o] - mean*sc;
  }
}

// ---- BN apply + relu + transpose: bf16 C2 -> out (B,256,N) fp32
__global__ __launch_bounds__(256) void k_bn_out(const unsigned short* __restrict__ Cb, const float* __restrict__ scale,
                         const float* __restrict__ shift, float* __restrict__ out){
  __shared__ float tile[64][65];
  int bx = blockIdx.x;
  int by = blockIdx.y;
  int b  = blockIdx.z;
  int t = threadIdx.x; int tx = t & 63; int ty = t >> 6;
  const unsigned short* src = Cb + ((size_t)b*16384 + (size_t)bx*64)*256 + by*64;
  int o = by*64 + tx;
  float sc = scale[o], sh = shift[o];
  #pragma unroll
  for (int i = 0; i < 16; ++i){
    int n = ty*16 + i;
    float v = bf2f(src[(size_t)n*256 + tx]);
    tile[n][tx] = fmaxf(0.f, v*sc + sh);
  }
  __syncthreads();
  float* dst = out + ((size_t)b*256 + by*64)*16384 + (size_t)bx*64;
  #pragma unroll
  for (int i = 0; i < 16; ++i){
    int oo = ty*16 + i;
    dst[(size_t)oo*16384 + tx] = tile[tx][oo];
  }
}

extern "C" void kernel_launch(void* const* d_in, const int* in_sizes, int n_in,
                              void* d_out, int out_size, void* d_ws, size_t ws_size,
                              hipStream_t stream){
  const float* xyz1    = (const float*)d_in[0];
  const float* xyz2    = (const float*)d_in[1];
  const float* points1 = (const float*)d_in[2];
  const float* points2 = (const float*)d_in[3];
  const float* W0  = (const float*)d_in[4];
  const float* g0  = (const float*)d_in[6];
  const float* be0 = (const float*)d_in[7];
  const float* W1  = (const float*)d_in[8];
  const float* g1  = (const float*)d_in[10];
  const float* be1 = (const float*)d_in[11];

  char* w = (char*)d_ws;
  size_t o = 0;
  float* f2t = (float*)(w + o); o += 8388608;            // (B,S,256) fp32
  float4* sp = (float4*)(w + o); o += 131072;            // sorted pts
  int* sid   = (int*)(w + o);   o += 32768;              // sorted ids
  int* cst   = (int*)(w + o);   o += 40960;              // cell starts 2 x (NC+1)
  float* gbox= (float*)(w + o); o += 256;                // per-batch bbox
  int* qorder= (int*)(w + o);   o += 131072;             // sorted query ids
  int* qcst  = (int*)(w + o);   o += 40960;              // query cell starts
  int*   kidx= (int*)(w + o);   o += 393216;             // final idx
  float* kww = (float*)(w + o); o += 393216;             // final weights
  unsigned short* W0b = (unsigned short*)(w + o); o += 262144;
  unsigned short* W1b = (unsigned short*)(w + o); o += 131072;
  float* psum = (float*)(w + o); o += 262144;            // [256 o][256 nblk]
  float* psq  = (float*)(w + o); o += 262144;
  float* scale1 = (float*)(w + o); o += 1024;
  float* shift1 = (float*)(w + o); o += 1024;
  float* scale2 = (float*)(w + o); o += 1024;
  float* shift2 = (float*)(w + o); o += 1024;
  unsigned short* Xt = (unsigned short*)(w + o); size_t xto = o; o += 33554432;  // (32768,512) bf16
  unsigned short* C1b = (unsigned short*)(w + o); o += 16777216;   // (32768,256) bf16
  unsigned short* C2b = (unsigned short*)(w + xto);      // reuse Xt region

  k_build<<<2, 1024, 0, stream>>>(xyz2, sp, sid, cst, gbox);
  k_qbin<<<2, 1024, 0, stream>>>(xyz1, gbox, qorder, qcst);
  k_convert_w<<<512, 256, 0, stream>>>(W0, W1, W0b, W1b);
  k_tp2<<<dim3(64,4,2), 256, 0, stream>>>(points2, f2t);
  k_knn_gc<<<2048, 256, 0, stream>>>(xyz1, sp, sid, cst, gbox, qorder, qcst, kidx, kww);
  k_tp1<<<dim3(256,4,2), 256, 0, stream>>>(points1, Xt);
  k_interp<<<8192, 256, 0, stream>>>(f2t, kidx, kww, Xt);
  k_gemm<512><<<dim3(2,256), 256, 0, stream>>>(W0b, Xt, C1b, psum, psq);
  k_stats_f<<<256, 256, 0, stream>>>(psum, psq, g0, be0, scale1, shift1);
  k_gemm2<<<dim3(2,256), 256, 0, stream>>>(W1b, C1b, scale1, shift1, C2b, psum, psq);
  k_stats_f<<<256, 256, 0, stream>>>(psum, psq, g1, be1, scale2, shift2);
  k_bn_out<<<dim3(256,4,2), 256, 0, stream>>>(C2b, scale2, shift2, (float*)d_out);
}

// Round 12
// 249.853 us; speedup vs baseline: 2.8015x; 1.6568x over previous
//
#include <hip/hip_runtime.h>

#define G 16
#define NC (G*G*G)

typedef __attribute__((ext_vector_type(8))) short bf16x8;
typedef __attribute__((ext_vector_type(4))) float f32x4;
typedef __attribute__((ext_vector_type(8))) short short8v;

__device__ __forceinline__ unsigned short f2bf(float f){
  union { float f; unsigned u; } v; v.f = f;
  unsigned u = v.u;
  u += 0x7FFFu + ((u >> 16) & 1u);
  return (unsigned short)(u >> 16);
}

__device__ __forceinline__ float bf2f(unsigned short h){
  union { unsigned u; float f; } v; v.u = ((unsigned)h) << 16;
  return v.f;
}

__device__ __forceinline__ void gl_lds16(const void* g, void* l){
  __builtin_amdgcn_global_load_lds((const __attribute__((address_space(1))) unsigned*)g,
                                   (__attribute__((address_space(3))) unsigned*)l, 16, 0, 0);
}

// lexicographic (d, idx) sorted top-3 insert: ties -> lower index (== jax top_k),
// order-independent => exact under any scan order / conservative skips. (R10/R11-verified)
__device__ __forceinline__ void ins3L(float d, int s,
    float& m0, float& m1, float& m2, int& i0, int& i1, int& i2){
  bool c0 = (d < m0) || (d == m0 && s < i0);
  bool c1 = (d < m1) || (d == m1 && s < i1);
  bool c2 = (d < m2) || (d == m2 && s < i2);
  float n1d = c0 ? m0 : d;  int n1i = c0 ? i0 : s;
  float n2d = c1 ? m1 : d;  int n2i = c1 ? i1 : s;
  m0 = c0 ? d   : m0;  i0 = c0 ? s   : i0;
  m1 = c1 ? n1d : m1;  i1 = c1 ? n1i : i1;
  m2 = c2 ? n2d : m2;  i2 = c2 ? n2i : i2;
}

// ---- W fp32 -> bf16
__global__ __launch_bounds__(256) void k_convert_w(const float* __restrict__ W0, const float* __restrict__ W1,
                            unsigned short* __restrict__ W0b, unsigned short* __restrict__ W1b){
  int i = blockIdx.x*256 + threadIdx.x;
  if (i < 256*512) W0b[i] = f2bf(W0[i]);
  if (i < 256*256) W1b[i] = f2bf(W1[i]);
}

// ---- grid build for points: bbox -> histogram -> scan -> counting-sort. 1 block/batch. (R11-verified)
__global__ __launch_bounds__(1024) void k_build(const float* __restrict__ xyz2,
        float4* __restrict__ sp, int* __restrict__ sid,
        int* __restrict__ cst, float* __restrict__ box){
  int b = blockIdx.x, t = threadIdx.x;
  int lane = t & 63, wv = t >> 6;
  const float* px = xyz2 + (size_t)b*3*4096;
  float mnx=3.4e38f, mxx=-3.4e38f, mny=3.4e38f, mxy=-3.4e38f, mnz=3.4e38f, mxz=-3.4e38f;
  for (int i = t; i < 4096; i += 1024){
    float x = px[i], y = px[4096+i], z = px[8192+i];
    mnx=fminf(mnx,x); mxx=fmaxf(mxx,x);
    mny=fminf(mny,y); mxy=fmaxf(mxy,y);
    mnz=fminf(mnz,z); mxz=fmaxf(mxz,z);
  }
  #pragma unroll
  for (int d = 1; d < 64; d <<= 1){
    mnx=fminf(mnx,__shfl_xor(mnx,d)); mxx=fmaxf(mxx,__shfl_xor(mxx,d));
    mny=fminf(mny,__shfl_xor(mny,d)); mxy=fmaxf(mxy,__shfl_xor(mxy,d));
    mnz=fminf(mnz,__shfl_xor(mnz,d)); mxz=fmaxf(mxz,__shfl_xor(mxz,d));
  }
  __shared__ float rb[16][6];
  __shared__ float sbox[8];
  if (lane==0){ rb[wv][0]=mnx; rb[wv][1]=mxx; rb[wv][2]=mny; rb[wv][3]=mxy; rb[wv][4]=mnz; rb[wv][5]=mxz; }
  __syncthreads();
  if (t == 0){
    float a0=rb[0][0],a1=rb[0][1],a2=rb[0][2],a3=rb[0][3],a4=rb[0][4],a5=rb[0][5];
    for (int i=1;i<16;++i){
      a0=fminf(a0,rb[i][0]); a1=fmaxf(a1,rb[i][1]);
      a2=fminf(a2,rb[i][2]); a3=fmaxf(a3,rb[i][3]);
      a4=fminf(a4,rb[i][4]); a5=fmaxf(a5,rb[i][5]);
    }
    float hx = fmaxf((a1-a0)/G, 1e-6f), hy = fmaxf((a3-a2)/G, 1e-6f), hz = fmaxf((a5-a4)/G, 1e-6f);
    sbox[0]=a0; sbox[1]=a2; sbox[2]=a4; sbox[3]=hx; sbox[4]=hy; sbox[5]=hz;
    box[b*8+0]=a0; box[b*8+1]=a2; box[b*8+2]=a4;
    box[b*8+3]=hx; box[b*8+4]=hy; box[b*8+5]=hz;
  }
  __shared__ int cnt[NC];
  __shared__ int stt[NC+1];
  for (int i = t; i < NC; i += 1024) cnt[i] = 0;
  __syncthreads();
  float bmx=sbox[0], bmy=sbox[1], bmz=sbox[2];
  float ihx=1.0f/sbox[3], ihy=1.0f/sbox[4], ihz=1.0f/sbox[5];
  for (int i = t; i < 4096; i += 1024){
    float x = px[i], y = px[4096+i], z = px[8192+i];
    int cxi = min(G-1, max(0, (int)floorf((x-bmx)*ihx)));
    int cyi = min(G-1, max(0, (int)floorf((y-bmy)*ihy)));
    int czi = min(G-1, max(0, (int)floorf((z-bmz)*ihz)));
    atomicAdd(&cnt[(czi*G+cyi)*G+cxi], 1);
  }
  __syncthreads();
  int v0 = cnt[4*t], v1 = cnt[4*t+1], v2 = cnt[4*t+2], v3 = cnt[4*t+3];
  int loc = v0+v1+v2+v3;
  int incl = loc;
  #pragma unroll
  for (int d = 1; d < 64; d <<= 1){
    int up = __shfl_up(incl, d);
    if (lane >= d) incl += up;
  }
  __shared__ int wsum[16];
  __shared__ int wbase[16];
  if (lane == 63) wsum[wv] = incl;
  __syncthreads();
  if (t == 0){
    int acc = 0;
    for (int i=0;i<16;++i){ wbase[i]=acc; acc += wsum[i]; }
  }
  __syncthreads();
  int run = wbase[wv] + (incl - loc);
  stt[4*t] = run; run += v0;
  stt[4*t+1] = run; run += v1;
  stt[4*t+2] = run; run += v2;
  stt[4*t+3] = run;
  if (t == 0) stt[NC] = 4096;
  __syncthreads();
  cnt[4*t]=stt[4*t]; cnt[4*t+1]=stt[4*t+1]; cnt[4*t+2]=stt[4*t+2]; cnt[4*t+3]=stt[4*t+3];
  __syncthreads();
  for (int i = t; i < 4096; i += 1024){
    float x = px[i], y = px[4096+i], z = px[8192+i];
    int cxi = min(G-1, max(0, (int)floorf((x-bmx)*ihx)));
    int cyi = min(G-1, max(0, (int)floorf((y-bmy)*ihy)));
    int czi = min(G-1, max(0, (int)floorf((z-bmz)*ihz)));
    int cid = (czi*G+cyi)*G+cxi;
    int pos = atomicAdd(&cnt[cid], 1);
    float r2 = x*x + y*y + z*z;
    float4 o; o.x=x; o.y=y; o.z=z; o.w=r2;
    sp[(size_t)b*4096 + pos] = o;
    sid[(size_t)b*4096 + pos] = i;
  }
  __syncthreads();
  for (int i = t; i <= NC; i += 1024) cst[(size_t)b*(NC+1) + i] = stt[i];
}

// ---- bin queries into the point grid (locality only — any grouping is exact),
//      plus tail: per-group-of-8 bounding spheres over sorted candidates.
__global__ __launch_bounds__(1024) void k_qbin(const float* __restrict__ xyz1, const float* __restrict__ box,
        const float4* __restrict__ sp, int* __restrict__ qorder, float4* __restrict__ gm){
  int b = blockIdx.x, t = threadIdx.x;
  int lane = t & 63, wv = t >> 6;
  const float* q = xyz1 + (size_t)b*3*16384;
  const float* bx = box + b*8;
  float bmx=bx[0], bmy=bx[1], bmz=bx[2];
  float ihx=1.0f/bx[3], ihy=1.0f/bx[4], ihz=1.0f/bx[5];
  __shared__ int cnt[NC];
  __shared__ int stt[NC+1];
  for (int i = t; i < NC; i += 1024) cnt[i] = 0;
  __syncthreads();
  for (int i = t; i < 16384; i += 1024){
    float x = q[i], y = q[16384+i], z = q[32768+i];
    int cxi = min(G-1, max(0, (int)floorf((x-bmx)*ihx)));
    int cyi = min(G-1, max(0, (int)floorf((y-bmy)*ihy)));
    int czi = min(G-1, max(0, (int)floorf((z-bmz)*ihz)));
    atomicAdd(&cnt[(czi*G+cyi)*G+cxi], 1);
  }
  __syncthreads();
  int v0 = cnt[4*t], v1 = cnt[4*t+1], v2 = cnt[4*t+2], v3 = cnt[4*t+3];
  int loc = v0+v1+v2+v3;
  int incl = loc;
  #pragma unroll
  for (int d = 1; d < 64; d <<= 1){
    int up = __shfl_up(incl, d);
    if (lane >= d) incl += up;
  }
  __shared__ int wsum[16];
  __shared__ int wbase[16];
  if (lane == 63) wsum[wv] = incl;
  __syncthreads();
  if (t == 0){
    int acc = 0;
    for (int i=0;i<16;++i){ wbase[i]=acc; acc += wsum[i]; }
  }
  __syncthreads();
  int run = wbase[wv] + (incl - loc);
  stt[4*t] = run; run += v0;
  stt[4*t+1] = run; run += v1;
  stt[4*t+2] = run; run += v2;
  stt[4*t+3] = run;
  if (t == 0) stt[NC] = 16384;
  __syncthreads();
  cnt[4*t]=stt[4*t]; cnt[4*t+1]=stt[4*t+1]; cnt[4*t+2]=stt[4*t+2]; cnt[4*t+3]=stt[4*t+3];
  __syncthreads();
  for (int i = t; i < 16384; i += 1024){
    float x = q[i], y = q[16384+i], z = q[32768+i];
    int cxi = min(G-1, max(0, (int)floorf((x-bmx)*ihx)));
    int cyi = min(G-1, max(0, (int)floorf((y-bmy)*ihy)));
    int czi = min(G-1, max(0, (int)floorf((z-bmz)*ihz)));
    int cid = (czi*G+cyi)*G+cxi;
    int pos = atomicAdd(&cnt[cid], 1);
    qorder[(size_t)b*16384 + pos] = i;
  }
  // ---- group bounding spheres: 512 groups of 8 sorted candidates
  if (t < 512){
    const float4* P = sp + (size_t)b*4096;
    float4 pt[8];
    float sx=0.f, sy=0.f, sz=0.f;
    #pragma unroll
    for (int u=0;u<8;++u){
      pt[u] = P[t*8+u];
      sx += pt[u].x; sy += pt[u].y; sz += pt[u].z;
    }
    float cx = sx*0.125f, cy = sy*0.125f, cz = sz*0.125f;
    float r2m = 0.f;
    #pragma unroll
    for (int u=0;u<8;++u){
      float dx=pt[u].x-cx, dy=pt[u].y-cy, dz=pt[u].z-cz;
      r2m = fmaxf(r2m, dx*dx+dy*dy+dz*dz);
    }
    float4 o; o.x=cx; o.y=cy; o.z=cz; o.w = sqrtf(r2m) + 1e-3f;
    gm[(size_t)b*512 + t] = o;
  }
}

// ---- KNN: sorted-candidate scan, per-group-of-8 bounding-sphere skip. Exact.
//      8192 waves (8/SIMD); wave = (query-group of 64 sorted queries, chunk of 32 groups)
__global__ __launch_bounds__(256) void k_knn_sg(const float* __restrict__ xyz1,
        const float4* __restrict__ sp, const int* __restrict__ sid,
        const float4* __restrict__ gm, const int* __restrict__ qorder,
        float* __restrict__ pd, int* __restrict__ pi){
  int lane = threadIdx.x & 63;
  int wid = blockIdx.x*4 + (threadIdx.x >> 6);   // 0..8191
  int qg = wid >> 4;                              // 512 query-groups
  int chunk = wid & 15;                           // 16 chunks x 32 groups
  int b = qg >> 8;
  int qn = qorder[(size_t)b*16384 + (qg & 255)*64 + lane];
  const float* q = xyz1 + (size_t)b*3*16384;
  float qx = q[qn], qy = q[16384+qn], qz = q[32768+qn];
  float r1 = qx*qx + qy*qy + qz*qz;
  const float4* P  = sp  + (size_t)b*4096;
  const int*    I  = sid + (size_t)b*4096;
  const float4* GM = gm  + (size_t)b*512;
  float m0=3.4e38f, m1=3.4e38f, m2=3.4e38f;
  int i0=0, i1=0, i2=0;
  float sm2 = 3.4e38f;                            // lazy sqrt(m2)+margin; inf -> never skip
  int g0 = chunk*32;
  for (int g = 0; g < 32; ++g){
    float4 c = GM[g0+g];
    float dx=qx-c.x, dy=qy-c.y, dz=qz-c.z;
    float dq2 = dx*dx + dy*dy + dz*dz;
    float tt = c.w + sm2;                         // rad + sqrt(m2) + margin
    bool need = !(dq2 > tt*tt);                   // conservative (inf-safe)
    if (__ballot(need)){
      int base = (g0+g)*8;
      #pragma unroll
      for (int u=0;u<8;++u){
        float4 p = P[base+u];
        float dot = qx*p.x + qy*p.y + qz*p.z;     // mul + fma + fma
        float d = (r1 + p.w) - 2.0f*dot;          // add + fma(-2)
        ins3L(d, I[base+u], m0,m1,m2, i0,i1,i2);
      }
      sm2 = sqrtf(m2) + 0.03f;                    // margin >> all fp32 slack (see analysis)
    }
  }
  size_t bb = (((size_t)b*16384 + qn)*16 + chunk)*3;
  pd[bb]=m0; pd[bb+1]=m1; pd[bb+2]=m2;
  pi[bb]=i0; pi[bb+1]=i1; pi[bb+2]=i2;
}

// ---- merge chunk partials (ins3L, order-free) -> final idx + weights
__global__ __launch_bounds__(256) void k_knn_merge(const float* __restrict__ pd, const int* __restrict__ pi,
                            int* __restrict__ ki, float* __restrict__ kw){
  size_t qq = (size_t)blockIdx.x*256 + threadIdx.x;
  float m0=3.4e38f,m1=3.4e38f,m2=3.4e38f; int i0=0,i1=0,i2=0;
  size_t base = qq*48;
  for (int c = 0; c < 48; ++c){
    ins3L(pd[base+c], pi[base+c], m0,m1,m2, i0,i1,i2);
  }
  float w0 = 1.0f/(m0+1e-8f), w1 = 1.0f/(m1+1e-8f), w2 = 1.0f/(m2+1e-8f);
  float inv = 1.0f/(w0+w1+w2);
  size_t kb = qq*3;
  ki[kb]=i0; ki[kb+1]=i1; ki[kb+2]=i2;
  kw[kb]=w0*inv; kw[kb+1]=w1*inv; kw[kb+2]=w2*inv;
}

// ---- transpose points2 (B,256,S) -> f2t (B,S,256) fp32
__global__ __launch_bounds__(256) void k_tp2(const float* __restrict__ p2, float* __restrict__ f2t){
  __shared__ float tile[64][65];
  int bx = blockIdx.x;
  int by = blockIdx.y;
  int b  = blockIdx.z;
  int t = threadIdx.x; int tx = t & 63; int ty = t >> 6;
  const float* src = p2 + ((size_t)b*256 + by*64)*4096 + bx*64;
  #pragma unroll
  for (int i = 0; i < 16; ++i){
    int c = ty*16 + i;
    tile[c][tx] = src[(size_t)c*4096 + tx];
  }
  __syncthreads();
  float* dst = f2t + ((size_t)b*4096 + (size_t)bx*64)*256 + by*64;
  #pragma unroll
  for (int i = 0; i < 16; ++i){
    int s = ty*16 + i;
    dst[(size_t)s*256 + tx] = tile[tx][s];
  }
}

// ---- transpose points1 (B,256,N) -> Xt (B*N, 512) cols [0,256) bf16
__global__ __launch_bounds__(256) void k_tp1(const float* __restrict__ p1, unsigned short* __restrict__ Xt){
  __shared__ float tile[64][65];
  int bx = blockIdx.x;
  int by = blockIdx.y;
  int b  = blockIdx.z;
  int t = threadIdx.x; int tx = t & 63; int ty = t >> 6;
  const float* src = p1 + ((size_t)b*256 + by*64)*16384 + (size_t)bx*64;
  #pragma unroll
  for (int i = 0; i < 16; ++i){
    int c = ty*16 + i;
    tile[c][tx] = src[(size_t)c*16384 + tx];
  }
  __syncthreads();
  unsigned short* dst = Xt + ((size_t)b*16384 + (size_t)bx*64)*512 + by*64;
  #pragma unroll
  for (int i = 0; i < 16; ++i){
    int n = ty*16 + i;
    dst[(size_t)n*512 + tx] = f2bf(tile[tx][n]);
  }
}

// ---- interp -> Xt cols [256,512) bf16
__global__ __launch_bounds__(256) void k_interp(const float* __restrict__ f2t, const int* __restrict__ ki,
                         const float* __restrict__ kw, unsigned short* __restrict__ Xt){
  int t = threadIdx.x;
  int g = t >> 6; int lane = t & 63;
  size_t q = (size_t)blockIdx.x*4 + g;
  int b = (int)(q >> 14);
  const float* f2 = f2t + (size_t)b*4096*256;
  size_t kb = q*3;
  int i0 = ki[kb], i1 = ki[kb+1], i2 = ki[kb+2];
  float w0 = kw[kb], w1 = kw[kb+1], w2 = kw[kb+2];
  const float4 a = *(const float4*)(f2 + (size_t)i0*256 + lane*4);
  const float4 c = *(const float4*)(f2 + (size_t)i1*256 + lane*4);
  const float4 e = *(const float4*)(f2 + (size_t)i2*256 + lane*4);
  ushort4 o;
  o.x = f2bf(w0*a.x + w1*c.x + w2*e.x);
  o.y = f2bf(w0*a.y + w1*c.y + w2*e.y);
  o.z = f2bf(w0*a.z + w1*c.z + w2*e.z);
  o.w = f2bf(w0*a.w + w1*c.w + w2*e.w);
  *(ushort4*)(Xt + q*512 + 256 + lane*4) = o;
}

// ---- NT MFMA GEMM + fused BN-stat partials; bf16 output (gemm1)
template<int K>
__global__ __launch_bounds__(256) void k_gemm(const unsigned short* __restrict__ A,
                       const unsigned short* __restrict__ Bm,
                       unsigned short* __restrict__ Cb,
                       float* __restrict__ psum, float* __restrict__ psq){
  __shared__ unsigned short As[128*32];
  __shared__ unsigned short Bs[128*32];
  __shared__ float redS[2][128];
  __shared__ float redQ[2][128];
  int t = threadIdx.x;
  int bo = blockIdx.x * 128;
  size_t bn = (size_t)blockIdx.y * 128;
  int w = t >> 6, l = t & 63;
  int wr = w >> 1, wc = w & 1;
  f32x4 acc[4][4] = {};

  const char* Ap = (const char*)A;
  const char* Bp = (const char*)Bm;
  int r0 = t >> 2;
  int cb = (t & 3) * 16;
  for (int k0 = 0; k0 < K; k0 += 32){
    __syncthreads();
    #pragma unroll
    for (int p = 0; p < 2; ++p){
      int off = (t + p*256)*16;
      int r = r0 + p*64;
      gl_lds16(Ap + (size_t)(bo + r)*(K*2) + (size_t)k0*2 + cb, (char*)As + off);
      gl_lds16(Bp + (bn + r)*(K*2) + (size_t)k0*2 + cb, (char*)Bs + off);
    }
    __syncthreads();
    bf16x8 af[4], bfr[4];
    int lr = l & 15, lk = (l >> 4) * 8;
    #pragma unroll
    for (int mt = 0; mt < 4; ++mt)
      af[mt] = *(const bf16x8*)(As + (wr*64 + mt*16 + lr)*32 + lk);
    #pragma unroll
    for (int nt = 0; nt < 4; ++nt)
      bfr[nt] = *(const bf16x8*)(Bs + (wc*64 + nt*16 + lr)*32 + lk);
    #pragma unroll
    for (int mt = 0; mt < 4; ++mt)
      #pragma unroll
      for (int nt = 0; nt < 4; ++nt)
        acc[mt][nt] = __builtin_amdgcn_mfma_f32_16x16x32_bf16(af[mt], bfr[nt], acc[mt][nt], 0, 0, 0);
  }
  int lo = (l >> 4) * 4, ln = l & 15;
  #pragma unroll
  for (int mt = 0; mt < 4; ++mt){
    #pragma unroll
    for (int nt = 0; nt < 4; ++nt){
      size_t n = bn + wc*64 + nt*16 + ln;
      int o = bo + wr*64 + mt*16 + lo;
      ushort4 ov;
      ov.x = f2bf(acc[mt][nt][0]); ov.y = f2bf(acc[mt][nt][1]);
      ov.z = f2bf(acc[mt][nt][2]); ov.w = f2bf(acc[mt][nt][3]);
      *(ushort4*)(Cb + n*256 + o) = ov;
    }
  }
  float ps[16], pq[16];
  #pragma unroll
  for (int mt = 0; mt < 4; ++mt){
    #pragma unroll
    for (int j = 0; j < 4; ++j){
      float s = 0.f, qv = 0.f;
      #pragma unroll
      for (int nt = 0; nt < 4; ++nt){
        float v = acc[mt][nt][j];
        s += v; qv += v*v;
      }
      ps[mt*4+j] = s; pq[mt*4+j] = qv;
    }
  }
  #pragma unroll
  for (int dlt = 1; dlt < 16; dlt <<= 1){
    #pragma unroll
    for (int i = 0; i < 16; ++i){
      ps[i] += __shfl_xor(ps[i], dlt);
      pq[i] += __shfl_xor(pq[i], dlt);
    }
  }
  if ((l & 15) == 0){
    #pragma unroll
    for (int mt = 0; mt < 4; ++mt){
      #pragma unroll
      for (int j = 0; j < 4; ++j){
        int ol = wr*64 + mt*16 + (l>>4)*4 + j;
        redS[wc][ol] = ps[mt*4+j];
        redQ[wc][ol] = pq[mt*4+j];
      }
    }
  }
  __syncthreads();
  if (t < 128){
    psum[(size_t)(bo + t)*256 + blockIdx.y] = redS[0][t] + redS[1][t];
    psq [(size_t)(bo + t)*256 + blockIdx.y] = redQ[0][t] + redQ[1][t];
  }
}

// ---- gemm2 with fused BN-apply+ReLU on the B operand
__global__ __launch_bounds__(256) void k_gemm2(const unsigned short* __restrict__ A,
                       const unsigned short* __restrict__ C1,
                       const float* __restrict__ scale, const float* __restrict__ shift,
                       unsigned short* __restrict__ Cb,
                       float* __restrict__ psum, float* __restrict__ psq){
  const int K = 256;
  __shared__ unsigned short As[128*32];
  __shared__ unsigned short Bs[128*32];
  __shared__ float redS[2][128];
  __shared__ float redQ[2][128];
  int t = threadIdx.x;
  int bo = blockIdx.x * 128;
  size_t bn = (size_t)blockIdx.y * 128;
  int w = t >> 6, l = t & 63;
  int wr = w >> 1, wc = w & 1;
  f32x4 acc[4][4] = {};

  const char* Ap = (const char*)A;
  int r0 = t >> 2;
  int cb = (t & 3) * 16;
  int ce0 = (t & 3) * 8;
  for (int k0 = 0; k0 < K; k0 += 32){
    int ce = k0 + ce0;
    float4 a0 = *(const float4*)(scale+ce); float4 a1 = *(const float4*)(scale+ce+4);
    float4 b0 = *(const float4*)(shift+ce); float4 b1 = *(const float4*)(shift+ce+4);
    float sc[8] = {a0.x,a0.y,a0.z,a0.w,a1.x,a1.y,a1.z,a1.w};
    float sh[8] = {b0.x,b0.y,b0.z,b0.w,b1.x,b1.y,b1.z,b1.w};
    short8v vin[2];
    #pragma unroll
    for (int p = 0; p < 2; ++p){
      int r = r0 + p*64;
      vin[p] = *(const short8v*)(C1 + (bn + r)*256 + ce);
    }
    __syncthreads();
    #pragma unroll
    for (int p = 0; p < 2; ++p){
      int r = r0 + p*64;
      gl_lds16(Ap + (size_t)(bo + r)*(K*2) + (size_t)k0*2 + cb, (char*)As + (t + p*256)*16);
    }
    #pragma unroll
    for (int p = 0; p < 2; ++p){
      short8v pv;
      #pragma unroll
      for (int j = 0; j < 8; ++j){
        float y = fmaxf(0.f, bf2f((unsigned short)vin[p][j])*sc[j] + sh[j]);
        pv[j] = (short)f2bf(y);
      }
      *(short8v*)((char*)Bs + (t + p*256)*16) = pv;
    }
    __syncthreads();
    bf16x8 af[4], bfr[4];
    int lr = l & 15, lk = (l >> 4) * 8;
    #pragma unroll
    for (int mt = 0; mt < 4; ++mt)
      af[mt] = *(const bf16x8*)(As + (wr*64 + mt*16 + lr)*32 + lk);
    #pragma unroll
    for (int nt = 0; nt < 4; ++nt)
      bfr[nt] = *(const bf16x8*)(Bs + (wc*64 + nt*16 + lr)*32 + lk);
    #pragma unroll
    for (int mt = 0; mt < 4; ++mt)
      #pragma unroll
      for (int nt = 0; nt < 4; ++nt)
        acc[mt][nt] = __builtin_amdgcn_mfma_f32_16x16x32_bf16(af[mt], bfr[nt], acc[mt][nt], 0, 0, 0);
  }
  int lo = (l >> 4) * 4, ln = l & 15;
  #pragma unroll
  for (int mt = 0; mt < 4; ++mt){
    #pragma unroll
    for (int nt = 0; nt < 4; ++nt){
      size_t n = bn + wc*64 + nt*16 + ln;
      int o = bo + wr*64 + mt*16 + lo;
      ushort4 ov;
      ov.x = f2bf(acc[mt][nt][0]); ov.y = f2bf(acc[mt][nt][1]);
      ov.z = f2bf(acc[mt][nt][2]); ov.w = f2bf(acc[mt][nt][3]);
      *(ushort4*)(Cb + n*256 + o) = ov;
    }
  }
  float ps[16], pq[16];
  #pragma unroll
  for (int mt = 0; mt < 4; ++mt){
    #pragma unroll
    for (int j = 0; j < 4; ++j){
      float s = 0.f, qv = 0.f;
      #pragma unroll
      for (int nt = 0; nt < 4; ++nt){
        float v = acc[mt][nt][j];
        s += v; qv += v*v;
      }
      ps[mt*4+j] = s; pq[mt*4+j] = qv;
    }
  }
  #pragma unroll
  for (int dlt = 1; dlt < 16; dlt <<= 1){
    #pragma unroll
    for (int i = 0; i < 16; ++i){
      ps[i] += __shfl_xor(ps[i], dlt);
      pq[i] += __shfl_xor(pq[i], dlt);
    }
  }
  if ((l & 15) == 0){
    #pragma unroll
    for (int mt = 0; mt < 4; ++mt){
      #pragma unroll
      for (int j = 0; j < 4; ++j){
        int ol = wr*64 + mt*16 + (l>>4)*4 + j;
        redS[wc][ol] = ps[mt*4+j];
        redQ[wc][ol] = pq[mt*4+j];
      }
    }
  }
  __syncthreads();
  if (t < 128){
    psum[(size_t)(bo + t)*256 + blockIdx.y] = redS[0][t] + redS[1][t];
    psq [(size_t)(bo + t)*256 + blockIdx.y] = redQ[0][t] + redQ[1][t];
  }
}

// ---- finalize BN stats
__global__ __launch_bounds__(256) void k_stats_f(const float* __restrict__ psum, const float* __restrict__ psq,
                          const float* __restrict__ gamma, const float* __restrict__ beta,
                          float* __restrict__ scale, float* __restrict__ shift){
  int o = blockIdx.x; int t = threadIdx.x;
  float s = psum[(size_t)o*256 + t];
  float q = psq [(size_t)o*256 + t];
  #pragma unroll
  for (int d = 1; d < 64; d <<= 1){
    s += __shfl_xor(s, d);
    q += __shfl_xor(q, d);
  }
  __shared__ float ls[4], lq[4];
  if ((t & 63) == 0){ ls[t>>6] = s; lq[t>>6] = q; }
  __syncthreads();
  if (t == 0){
    float S = ls[0]+ls[1]+ls[2]+ls[3];
    float Q = lq[0]+lq[1]+lq[2]+lq[3];
    const float invc = 1.0f/32768.0f;
    float mean = S*invc;
    float var = Q*invc - mean*mean;
    float sc = gamma[o]*rsqrtf(var + 1e-5f);
    scale[o] = sc;
    shift[o] = beta[o] - mean*sc;
  }
}

// ---- BN apply + relu + transpose: bf16 C2 -> out (B,256,N) fp32
__global__ __launch_bounds__(256) void k_bn_out(const unsigned short* __restrict__ Cb, const float* __restrict__ scale,
                         const float* __restrict__ shift, float* __restrict__ out){
  __shared__ float tile[64][65];
  int bx = blockIdx.x;
  int by = blockIdx.y;
  int b  = blockIdx.z;
  int t = threadIdx.x; int tx = t & 63; int ty = t >> 6;
  const unsigned short* src = Cb + ((size_t)b*16384 + (size_t)bx*64)*256 + by*64;
  int o = by*64 + tx;
  float sc = scale[o], sh = shift[o];
  #pragma unroll
  for (int i = 0; i < 16; ++i){
    int n = ty*16 + i;
    float v = bf2f(src[(size_t)n*256 + tx]);
    tile[n][tx] = fmaxf(0.f, v*sc + sh);
  }
  __syncthreads();
  float* dst = out + ((size_t)b*256 + by*64)*16384 + (size_t)bx*64;
  #pragma unroll
  for (int i = 0; i < 16; ++i){
    int oo = ty*16 + i;
    dst[(size_t)oo*16384 + tx] = tile[tx][oo];
  }
}

extern "C" void kernel_launch(void* const* d_in, const int* in_sizes, int n_in,
                              void* d_out, int out_size, void* d_ws, size_t ws_size,
                              hipStream_t stream){
  const float* xyz1    = (const float*)d_in[0];
  const float* xyz2    = (const float*)d_in[1];
  const float* points1 = (const float*)d_in[2];
  const float* points2 = (const float*)d_in[3];
  const float* W0  = (const float*)d_in[4];
  const float* g0  = (const float*)d_in[6];
  const float* be0 = (const float*)d_in[7];
  const float* W1  = (const float*)d_in[8];
  const float* g1  = (const float*)d_in[10];
  const float* be1 = (const float*)d_in[11];

  char* w = (char*)d_ws;
  size_t o = 0;
  float* f2t = (float*)(w + o); o += 8388608;            // (B,S,256) fp32
  float4* sp = (float4*)(w + o); o += 131072;            // sorted pts
  int* sid   = (int*)(w + o);   o += 32768;              // sorted ids
  int* cst   = (int*)(w + o);   o += 40960;              // cell starts (build scratch)
  float* gbox= (float*)(w + o); o += 256;                // per-batch bbox
  int* qorder= (int*)(w + o);   o += 131072;             // sorted query ids
  float4* gm = (float4*)(w + o); o += 16384;             // group spheres
  int*   kidx= (int*)(w + o);   o += 393216;             // final idx
  float* kww = (float*)(w + o); o += 393216;             // final weights
  unsigned short* W0b = (unsigned short*)(w + o); o += 262144;
  unsigned short* W1b = (unsigned short*)(w + o); o += 131072;
  float* psum = (float*)(w + o); o += 262144;            // [256 o][256 nblk]
  float* psq  = (float*)(w + o); o += 262144;
  float* scale1 = (float*)(w + o); o += 1024;
  float* shift1 = (float*)(w + o); o += 1024;
  float* scale2 = (float*)(w + o); o += 1024;
  float* shift2 = (float*)(w + o); o += 1024;
  float* kpd = (float*)(w + o); o += 6291456;            // per-chunk top3 d
  int*   kpi = (int*)(w + o);   o += 6291456;            // per-chunk top3 idx
  unsigned short* Xt = (unsigned short*)(w + o); size_t xto = o; o += 33554432;  // (32768,512) bf16
  unsigned short* C1b = (unsigned short*)(w + o); o += 16777216;   // (32768,256) bf16
  unsigned short* C2b = (unsigned short*)(w + xto);      // reuse Xt region

  k_build<<<2, 1024, 0, stream>>>(xyz2, sp, sid, cst, gbox);
  k_qbin<<<2, 1024, 0, stream>>>(xyz1, gbox, sp, qorder, gm);
  k_convert_w<<<512, 256, 0, stream>>>(W0, W1, W0b, W1b);
  k_tp2<<<dim3(64,4,2), 256, 0, stream>>>(points2, f2t);
  k_knn_sg<<<2048, 256, 0, stream>>>(xyz1, sp, sid, gm, qorder, kpd, kpi);
  k_knn_merge<<<128, 256, 0, stream>>>(kpd, kpi, kidx, kww);
  k_tp1<<<dim3(256,4,2), 256, 0, stream>>>(points1, Xt);
  k_interp<<<8192, 256, 0, stream>>>(f2t, kidx, kww, Xt);
  k_gemm<512><<<dim3(2,256), 256, 0, stream>>>(W0b, Xt, C1b, psum, psq);
  k_stats_f<<<256, 256, 0, stream>>>(psum, psq, g0, be0, scale1, shift1);
  k_gemm2<<<dim3(2,256), 256, 0, stream>>>(W1b, C1b, scale1, shift1, C2b, psum, psq);
  k_stats_f<<<256, 256, 0, stream>>>(psum, psq, g1, be1, scale2, shift2);
  k_bn_out<<<dim3(256,4,2), 256, 0, stream>>>(C2b, scale2, shift2, (float*)d_out);
}

// Round 13
// 156.132 us; speedup vs baseline: 4.4831x; 1.6003x over previous
//
#include <hip/hip_runtime.h>

#define NCHUNK 16

typedef __attribute__((ext_vector_type(8))) short bf16x8;
typedef __attribute__((ext_vector_type(4))) float f32x4;
typedef __attribute__((ext_vector_type(2))) float f32x2;
typedef __attribute__((ext_vector_type(8))) short short8v;

struct PairRec { f32x2 x, y, z, w; };   // 2 candidates: {x0,x1},{y0,y1},{z0,z1},{r2_0,r2_1}

__device__ __forceinline__ unsigned short f2bf(float f){
  union { float f; unsigned u; } v; v.f = f;
  unsigned u = v.u;
  u += 0x7FFFu + ((u >> 16) & 1u);
  return (unsigned short)(u >> 16);
}

__device__ __forceinline__ float bf2f(unsigned short h){
  union { unsigned u; float f; } v; v.u = ((unsigned)h) << 16;
  return v.f;
}

__device__ __forceinline__ void gl_lds16(const void* g, void* l){
  __builtin_amdgcn_global_load_lds((const __attribute__((address_space(1))) unsigned*)g,
                                   (__attribute__((address_space(3))) unsigned*)l, 16, 0, 0);
}

// packed distance, 2 candidates/instr. Per-component op sequence is FORCED to
// mul, fma, fma, add, fma — identical to the scalar pattern of rounds 1-7. (R9-verified)
__device__ __forceinline__ f32x2 pkdist(PairRec p, f32x2 qx2, f32x2 qy2, f32x2 qz2, f32x2 r12){
  f32x2 dot = p.x * qx2;                                   // v_pk_mul_f32
  dot = __builtin_elementwise_fma(p.y, qy2, dot);          // v_pk_fma_f32
  dot = __builtin_elementwise_fma(p.z, qz2, dot);          // v_pk_fma_f32
  f32x2 t = r12 + p.w;                                     // v_pk_add_f32
  f32x2 n2 = {-2.0f, -2.0f};
  return __builtin_elementwise_fma(dot, n2, t);            // v_pk_fma_f32
}

// sorted top-3 insert with indices (round-6/9 verified, exact)
__device__ __forceinline__ void ins3(float d, int s,
    float& m0, float& m1, float& m2, int& i0, int& i1, int& i2){
  bool c0 = d < m0, c1 = d < m1, c2 = d < m2;
  float om0 = m0, om1 = m1;
  m0 = fminf(om0, d);
  m1 = __builtin_amdgcn_fmed3f(om0, om1, d);
  m2 = __builtin_amdgcn_fmed3f(om1, m2, d);
  int j1 = c0 ? i0 : s;
  int j2 = c1 ? i1 : s;
  i0 = c0 ? s  : i0;
  i1 = c1 ? j1 : i1;
  i2 = c2 ? j2 : i2;
}

// ---- W fp32 -> bf16, plus pack xyz2 into pair-records (R9-verified)
__global__ __launch_bounds__(256) void k_convert_w(const float* __restrict__ W0, const float* __restrict__ W1,
                            unsigned short* __restrict__ W0b, unsigned short* __restrict__ W1b,
                            const float* __restrict__ xyz2, float* __restrict__ p2pp){
  int i = blockIdx.x*256 + threadIdx.x;
  if (i < 256*512) W0b[i] = f2bf(W0[i]);
  if (i < 256*256) W1b[i] = f2bf(W1[i]);
  if (i < 8192){
    int b = i >> 12, s = i & 4095;
    const float* px = xyz2 + (size_t)b*3*4096;
    float x = px[s], y = px[4096+s], z = px[8192+s];
    float r2 = x*x + y*y + z*z;
    size_t base = (size_t)b*16384 + (size_t)(s >> 1)*8 + (s & 1);
    p2pp[base+0] = x; p2pp[base+2] = y; p2pp[base+4] = z; p2pp[base+6] = r2;
  }
}

// ---- transpose points2 (B,256,S) -> f2t (B,S,256) fp32
__global__ __launch_bounds__(256) void k_tp2(const float* __restrict__ p2, float* __restrict__ f2t){
  __shared__ float tile[64][65];
  int bx = blockIdx.x;
  int by = blockIdx.y;
  int b  = blockIdx.z;
  int t = threadIdx.x; int tx = t & 63; int ty = t >> 6;
  const float* src = p2 + ((size_t)b*256 + by*64)*4096 + bx*64;
  #pragma unroll
  for (int i = 0; i < 16; ++i){
    int c = ty*16 + i;
    tile[c][tx] = src[(size_t)c*4096 + tx];
  }
  __syncthreads();
  float* dst = f2t + ((size_t)b*4096 + (size_t)bx*64)*256 + by*64;
  #pragma unroll
  for (int i = 0; i < 16; ++i){
    int s = ty*16 + i;
    dst[(size_t)s*256 + tx] = tile[tx][s];
  }
}

// ---- KNN: single pass, packed-pair distances + exact ins3 (R9-verified, 64 µs)
__global__ __launch_bounds__(256) void k_knn(const float* __restrict__ xyz1, const float* __restrict__ p2pp,
                      float* __restrict__ pd, int* __restrict__ pi){
  int b = blockIdx.z, cc = blockIdx.y;
  int n = blockIdx.x*256 + threadIdx.x;
  const float* q = xyz1 + (size_t)b*3*16384;
  float qx = q[n], qy = q[16384+n], qz = q[32768+n];
  float r1 = qx*qx + qy*qy + qz*qz;
  f32x2 qx2 = {qx,qx}, qy2 = {qy,qy}, qz2 = {qz,qz}, r12 = {r1,r1};
  const int NP = (4096/NCHUNK)/2;        // pairs per chunk = 128
  int s0 = cc*(4096/NCHUNK);
  const PairRec* pp = (const PairRec*)p2pp + (size_t)b*2048 + cc*NP;
  float m0=3.4e38f, m1=3.4e38f, m2=3.4e38f;
  int i0=0, i1=0, i2=0;
  for (int g = 0; g < NP/4; ++g){
    PairRec pA = pp[g*4+0], pB = pp[g*4+1], pC = pp[g*4+2], pD = pp[g*4+3];
    int sb = s0 + g*8;
    f32x2 dA = pkdist(pA, qx2, qy2, qz2, r12);
    ins3(dA.x, sb+0, m0,m1,m2, i0,i1,i2);
    ins3(dA.y, sb+1, m0,m1,m2, i0,i1,i2);
    f32x2 dB = pkdist(pB, qx2, qy2, qz2, r12);
    ins3(dB.x, sb+2, m0,m1,m2, i0,i1,i2);
    ins3(dB.y, sb+3, m0,m1,m2, i0,i1,i2);
    f32x2 dC = pkdist(pC, qx2, qy2, qz2, r12);
    ins3(dC.x, sb+4, m0,m1,m2, i0,i1,i2);
    ins3(dC.y, sb+5, m0,m1,m2, i0,i1,i2);
    f32x2 dD = pkdist(pD, qx2, qy2, qz2, r12);
    ins3(dD.x, sb+6, m0,m1,m2, i0,i1,i2);
    ins3(dD.y, sb+7, m0,m1,m2, i0,i1,i2);
  }
  size_t base = (((size_t)b*16384 + n)*NCHUNK + cc)*3;
  pd[base]=m0; pd[base+1]=m1; pd[base+2]=m2;
  pi[base]=i0; pi[base+1]=i1; pi[base+2]=i2;
}

__global__ __launch_bounds__(256) void k_knn_merge(const float* __restrict__ pd, const int* __restrict__ pi,
                            int* __restrict__ ki, float* __restrict__ kw){
  size_t qq = (size_t)blockIdx.x*256 + threadIdx.x;
  float d0=3.4e38f,d1=3.4e38f,d2=3.4e38f; int i0=0,i1=0,i2=0;
  size_t base = qq*NCHUNK*3;
  for (int c = 0; c < NCHUNK*3; ++c){
    float d = pd[base+c]; int s = pi[base+c];
    if (d < d2){
      if (d < d1){
        d2=d1; i2=i1;
        if (d < d0){ d1=d0; i1=i0; d0=d; i0=s; }
        else       { d1=d; i1=s; }
      } else { d2=d; i2=s; }
    }
  }
  float w0 = 1.0f/(d0+1e-8f), w1 = 1.0f/(d1+1e-8f), w2 = 1.0f/(d2+1e-8f);
  float inv = 1.0f/(w0+w1+w2);
  size_t kb = qq*3;
  ki[kb]=i0; ki[kb+1]=i1; ki[kb+2]=i2;
  kw[kb]=w0*inv; kw[kb+1]=w1*inv; kw[kb+2]=w2*inv;
}

// ---- interp -> Yi (32768 x 256) bf16
__global__ __launch_bounds__(256) void k_interp(const float* __restrict__ f2t, const int* __restrict__ ki,
                         const float* __restrict__ kw, unsigned short* __restrict__ Yi){
  int t = threadIdx.x;
  int g = t >> 6; int lane = t & 63;
  size_t q = (size_t)blockIdx.x*4 + g;
  int b = (int)(q >> 14);
  const float* f2 = f2t + (size_t)b*4096*256;
  size_t kb = q*3;
  int i0 = ki[kb], i1 = ki[kb+1], i2 = ki[kb+2];
  float w0 = kw[kb], w1 = kw[kb+1], w2 = kw[kb+2];
  const float4 a = *(const float4*)(f2 + (size_t)i0*256 + lane*4);
  const float4 c = *(const float4*)(f2 + (size_t)i1*256 + lane*4);
  const float4 e = *(const float4*)(f2 + (size_t)i2*256 + lane*4);
  ushort4 o;
  o.x = f2bf(w0*a.x + w1*c.x + w2*e.x);
  o.y = f2bf(w0*a.y + w1*c.y + w2*e.y);
  o.z = f2bf(w0*a.z + w1*c.z + w2*e.z);
  o.w = f2bf(w0*a.w + w1*c.w + w2*e.w);
  *(ushort4*)(Yi + q*256 + lane*4) = o;
}

// ---- gemm1: A = W0b (256x512), B rows = [points1^T | Yi] built in staging.
//      cols 0-255: register-transpose from points1 fp32; cols 256-511: gl_lds16 from Yi.
__global__ __launch_bounds__(256) void k_gemm1(const unsigned short* __restrict__ A,
                       const float* __restrict__ p1,
                       const unsigned short* __restrict__ Yi,
                       unsigned short* __restrict__ Cb,
                       float* __restrict__ psum, float* __restrict__ psq){
  const int K = 512;
  __shared__ unsigned short As[128*32];
  __shared__ unsigned short Bs[128*32];
  __shared__ float redS[2][128];
  __shared__ float redQ[2][128];
  int t = threadIdx.x;
  int bo = blockIdx.x * 128;
  size_t bn = (size_t)blockIdx.y * 128;
  int b = (int)(bn >> 14);
  int nn0 = (int)(bn & 16383);
  int w = t >> 6, l = t & 63;
  int wr = w >> 1, wc = w & 1;
  f32x4 acc[4][4] = {};

  const char* Ap = (const char*)A;
  int r0 = t >> 2;
  int cbb = (t & 3) * 16;
  int pch = t & 15;       // channel pair
  int seg = t >> 4;       // n segment (8 each)
  for (int k0 = 0; k0 < K; k0 += 32){
    __syncthreads();
    #pragma unroll
    for (int p = 0; p < 2; ++p){
      int off = (t + p*256)*16;
      int r = r0 + p*64;
      gl_lds16(Ap + (size_t)(bo + r)*(K*2) + (size_t)k0*2 + cbb, (char*)As + off);
    }
    if (k0 < 256){
      const float* s0 = p1 + ((size_t)(b*256 + k0 + 2*pch))*16384 + nn0 + seg*8;
      const float* s1 = s0 + 16384;
      float4 a0 = *(const float4*)(s0);
      float4 a1 = *(const float4*)(s0+4);
      float4 c0 = *(const float4*)(s1);
      float4 c1 = *(const float4*)(s1+4);
      float e0[8] = {a0.x,a0.y,a0.z,a0.w,a1.x,a1.y,a1.z,a1.w};
      float e1[8] = {c0.x,c0.y,c0.z,c0.w,c1.x,c1.y,c1.z,c1.w};
      #pragma unroll
      for (int i = 0; i < 8; ++i){
        unsigned v = ((unsigned)f2bf(e1[i]) << 16) | (unsigned)f2bf(e0[i]);
        *(unsigned*)((char*)Bs + (size_t)(seg*8 + i)*64 + pch*4) = v;
      }
    } else {
      #pragma unroll
      for (int p = 0; p < 2; ++p){
        int off = (t + p*256)*16;
        int r = r0 + p*64;
        gl_lds16((const char*)Yi + (bn + r)*512 + (size_t)(k0-256)*2 + cbb, (char*)Bs + off);
      }
    }
    __syncthreads();
    bf16x8 af[4], bfr[4];
    int lr = l & 15, lk = (l >> 4) * 8;
    #pragma unroll
    for (int mt = 0; mt < 4; ++mt)
      af[mt] = *(const bf16x8*)(As + (wr*64 + mt*16 + lr)*32 + lk);
    #pragma unroll
    for (int nt = 0; nt < 4; ++nt)
      bfr[nt] = *(const bf16x8*)(Bs + (wc*64 + nt*16 + lr)*32 + lk);
    #pragma unroll
    for (int mt = 0; mt < 4; ++mt)
      #pragma unroll
      for (int nt = 0; nt < 4; ++nt)
        acc[mt][nt] = __builtin_amdgcn_mfma_f32_16x16x32_bf16(af[mt], bfr[nt], acc[mt][nt], 0, 0, 0);
  }
  int lo = (l >> 4) * 4, ln = l & 15;
  #pragma unroll
  for (int mt = 0; mt < 4; ++mt){
    #pragma unroll
    for (int nt = 0; nt < 4; ++nt){
      size_t n = bn + wc*64 + nt*16 + ln;
      int o = bo + wr*64 + mt*16 + lo;
      ushort4 ov;
      ov.x = f2bf(acc[mt][nt][0]); ov.y = f2bf(acc[mt][nt][1]);
      ov.z = f2bf(acc[mt][nt][2]); ov.w = f2bf(acc[mt][nt][3]);
      *(ushort4*)(Cb + n*256 + o) = ov;
    }
  }
  float ps[16], pq[16];
  #pragma unroll
  for (int mt = 0; mt < 4; ++mt){
    #pragma unroll
    for (int j = 0; j < 4; ++j){
      float s = 0.f, qv = 0.f;
      #pragma unroll
      for (int nt = 0; nt < 4; ++nt){
        float v = acc[mt][nt][j];
        s += v; qv += v*v;
      }
      ps[mt*4+j] = s; pq[mt*4+j] = qv;
    }
  }
  #pragma unroll
  for (int dlt = 1; dlt < 16; dlt <<= 1){
    #pragma unroll
    for (int i = 0; i < 16; ++i){
      ps[i] += __shfl_xor(ps[i], dlt);
      pq[i] += __shfl_xor(pq[i], dlt);
    }
  }
  if ((l & 15) == 0){
    #pragma unroll
    for (int mt = 0; mt < 4; ++mt){
      #pragma unroll
      for (int j = 0; j < 4; ++j){
        int ol = wr*64 + mt*16 + (l>>4)*4 + j;
        redS[wc][ol] = ps[mt*4+j];
        redQ[wc][ol] = pq[mt*4+j];
      }
    }
  }
  __syncthreads();
  if (t < 128){
    psum[(size_t)(bo + t)*256 + blockIdx.y] = redS[0][t] + redS[1][t];
    psq [(size_t)(bo + t)*256 + blockIdx.y] = redQ[0][t] + redQ[1][t];
  }
}

// ---- gemm2 with fused BN-apply+ReLU on the B operand (R9-verified)
__global__ __launch_bounds__(256) void k_gemm2(const unsigned short* __restrict__ A,
                       const unsigned short* __restrict__ C1,
                       const float* __restrict__ scale, const float* __restrict__ shift,
                       unsigned short* __restrict__ Cb,
                       float* __restrict__ psum, float* __restrict__ psq){
  const int K = 256;
  __shared__ unsigned short As[128*32];
  __shared__ unsigned short Bs[128*32];
  __shared__ float redS[2][128];
  __shared__ float redQ[2][128];
  int t = threadIdx.x;
  int bo = blockIdx.x * 128;
  size_t bn = (size_t)blockIdx.y * 128;
  int w = t >> 6, l = t & 63;
  int wr = w >> 1, wc = w & 1;
  f32x4 acc[4][4] = {};

  const char* Ap = (const char*)A;
  int r0 = t >> 2;
  int cbb = (t & 3) * 16;
  int ce0 = (t & 3) * 8;
  for (int k0 = 0; k0 < K; k0 += 32){
    int ce = k0 + ce0;
    float4 a0 = *(const float4*)(scale+ce); float4 a1 = *(const float4*)(scale+ce+4);
    float4 b0 = *(const float4*)(shift+ce); float4 b1 = *(const float4*)(shift+ce+4);
    float sc[8] = {a0.x,a0.y,a0.z,a0.w,a1.x,a1.y,a1.z,a1.w};
    float sh[8] = {b0.x,b0.y,b0.z,b0.w,b1.x,b1.y,b1.z,b1.w};
    short8v vin[2];
    #pragma unroll
    for (int p = 0; p < 2; ++p){
      int r = r0 + p*64;
      vin[p] = *(const short8v*)(C1 + (bn + r)*256 + ce);
    }
    __syncthreads();
    #pragma unroll
    for (int p = 0; p < 2; ++p){
      int r = r0 + p*64;
      gl_lds16(Ap + (size_t)(bo + r)*(K*2) + (size_t)k0*2 + cbb, (char*)As + (t + p*256)*16);
    }
    #pragma unroll
    for (int p = 0; p < 2; ++p){
      short8v pv;
      #pragma unroll
      for (int j = 0; j < 8; ++j){
        float y = fmaxf(0.f, bf2f((unsigned short)vin[p][j])*sc[j] + sh[j]);
        pv[j] = (short)f2bf(y);
      }
      *(short8v*)((char*)Bs + (t + p*256)*16) = pv;
    }
    __syncthreads();
    bf16x8 af[4], bfr[4];
    int lr = l & 15, lk = (l >> 4) * 8;
    #pragma unroll
    for (int mt = 0; mt < 4; ++mt)
      af[mt] = *(const bf16x8*)(As + (wr*64 + mt*16 + lr)*32 + lk);
    #pragma unroll
    for (int nt = 0; nt < 4; ++nt)
      bfr[nt] = *(const bf16x8*)(Bs + (wc*64 + nt*16 + lr)*32 + lk);
    #pragma unroll
    for (int mt = 0; mt < 4; ++mt)
      #pragma unroll
      for (int nt = 0; nt < 4; ++nt)
        acc[mt][nt] = __builtin_amdgcn_mfma_f32_16x16x32_bf16(af[mt], bfr[nt], acc[mt][nt], 0, 0, 0);
  }
  int lo = (l >> 4) * 4, ln = l & 15;
  #pragma unroll
  for (int mt = 0; mt < 4; ++mt){
    #pragma unroll
    for (int nt = 0; nt < 4; ++nt){
      size_t n = bn + wc*64 + nt*16 + ln;
      int o = bo + wr*64 + mt*16 + lo;
      ushort4 ov;
      ov.x = f2bf(acc[mt][nt][0]); ov.y = f2bf(acc[mt][nt][1]);
      ov.z = f2bf(acc[mt][nt][2]); ov.w = f2bf(acc[mt][nt][3]);
      *(ushort4*)(Cb + n*256 + o) = ov;
    }
  }
  float ps[16], pq[16];
  #pragma unroll
  for (int mt = 0; mt < 4; ++mt){
    #pragma unroll
    for (int j = 0; j < 4; ++j){
      float s = 0.f, qv = 0.f;
      #pragma unroll
      for (int nt = 0; nt < 4; ++nt){
        float v = acc[mt][nt][j];
        s += v; qv += v*v;
      }
      ps[mt*4+j] = s; pq[mt*4+j] = qv;
    }
  }
  #pragma unroll
  for (int dlt = 1; dlt < 16; dlt <<= 1){
    #pragma unroll
    for (int i = 0; i < 16; ++i){
      ps[i] += __shfl_xor(ps[i], dlt);
      pq[i] += __shfl_xor(pq[i], dlt);
    }
  }
  if ((l & 15) == 0){
    #pragma unroll
    for (int mt = 0; mt < 4; ++mt){
      #pragma unroll
      for (int j = 0; j < 4; ++j){
        int ol = wr*64 + mt*16 + (l>>4)*4 + j;
        redS[wc][ol] = ps[mt*4+j];
        redQ[wc][ol] = pq[mt*4+j];
      }
    }
  }
  __syncthreads();
  if (t < 128){
    psum[(size_t)(bo + t)*256 + blockIdx.y] = redS[0][t] + redS[1][t];
    psq [(size_t)(bo + t)*256 + blockIdx.y] = redQ[0][t] + redQ[1][t];
  }
}

// ---- finalize BN stats
__global__ __launch_bounds__(256) void k_stats_f(const float* __restrict__ psum, const float* __restrict__ psq,
                          const float* __restrict__ gamma, const float* __restrict__ beta,
                          float* __restrict__ scale, float* __restrict__ shift){
  int o = blockIdx.x; int t = threadIdx.x;
  float s = psum[(size_t)o*256 + t];
  float q = psq [(size_t)o*256 + t];
  #pragma unroll
  for (int d = 1; d < 64; d <<= 1){
    s += __shfl_xor(s, d);
    q += __shfl_xor(q, d);
  }
  __shared__ float ls[4], lq[4];
  if ((t & 63) == 0){ ls[t>>6] = s; lq[t>>6] = q; }
  __syncthreads();
  if (t == 0){
    float S = ls[0]+ls[1]+ls[2]+ls[3];
    float Q = lq[0]+lq[1]+lq[2]+lq[3];
    const float invc = 1.0f/32768.0f;
    float mean = S*invc;
    float var = Q*invc - mean*mean;
    float sc = gamma[o]*rsqrtf(var + 1e-5f);
    scale[o] = sc;
    shift[o] = beta[o] - mean*sc;
  }
}

// ---- BN apply + relu + transpose: bf16 C2 -> out (B,256,N) fp32
__global__ __launch_bounds__(256) void k_bn_out(const unsigned short* __restrict__ Cb, const float* __restrict__ scale,
                         const float* __restrict__ shift, float* __restrict__ out){
  __shared__ float tile[64][65];
  int bx = blockIdx.x;
  int by = blockIdx.y;
  int b  = blockIdx.z;
  int t = threadIdx.x; int tx = t & 63; int ty = t >> 6;
  const unsigned short* src = Cb + ((size_t)b*16384 + (size_t)bx*64)*256 + by*64;
  int o = by*64 + tx;
  float sc = scale[o], sh = shift[o];
  #pragma unroll
  for (int i = 0; i < 16; ++i){
    int n = ty*16 + i;
    float v = bf2f(src[(size_t)n*256 + tx]);
    tile[n][tx] = fmaxf(0.f, v*sc + sh);
  }
  __syncthreads();
  float* dst = out + ((size_t)b*256 + by*64)*16384 + (size_t)bx*64;
  #pragma unroll
  for (int i = 0; i < 16; ++i){
    int oo = ty*16 + i;
    dst[(size_t)oo*16384 + tx] = tile[tx][oo];
  }
}

extern "C" void kernel_launch(void* const* d_in, const int* in_sizes, int n_in,
                              void* d_out, int out_size, void* d_ws, size_t ws_size,
                              hipStream_t stream){
  const float* xyz1    = (const float*)d_in[0];
  const float* xyz2    = (const float*)d_in[1];
  const float* points1 = (const float*)d_in[2];
  const float* points2 = (const float*)d_in[3];
  const float* W0  = (const float*)d_in[4];
  const float* g0  = (const float*)d_in[6];
  const float* be0 = (const float*)d_in[7];
  const float* W1  = (const float*)d_in[8];
  const float* g1  = (const float*)d_in[10];
  const float* be1 = (const float*)d_in[11];

  char* w = (char*)d_ws;
  size_t o = 0;
  float* f2t = (float*)(w + o); o += 8388608;            // (B,S,256) fp32
  float* p2pp= (float*)(w + o); o += 131072;             // packed pair-records
  int*   kidx= (int*)(w + o);   o += 393216;             // final idx
  float* kww = (float*)(w + o); o += 393216;             // final weights
  unsigned short* W0b = (unsigned short*)(w + o); o += 262144;
  unsigned short* W1b = (unsigned short*)(w + o); o += 131072;
  float* psum = (float*)(w + o); o += 262144;            // [256 o][256 nblk]
  float* psq  = (float*)(w + o); o += 262144;
  float* scale1 = (float*)(w + o); o += 1024;
  float* shift1 = (float*)(w + o); o += 1024;
  float* scale2 = (float*)(w + o); o += 1024;
  float* shift2 = (float*)(w + o); o += 1024;
  float* kpd = (float*)(w + o); o += 6291456;            // per-chunk top3 d
  int*   kpi = (int*)(w + o);   o += 6291456;            // per-chunk top3 idx
  unsigned short* Yi  = (unsigned short*)(w + o); o += 16777216;  // interp (32768,256) bf16
  unsigned short* C1b = (unsigned short*)(w + o); o += 16777216;  // (32768,256) bf16
  unsigned short* C2b = (unsigned short*)(w + o); o += 16777216;  // (32768,256) bf16

  k_convert_w<<<512, 256, 0, stream>>>(W0, W1, W0b, W1b, xyz2, p2pp);
  k_tp2<<<dim3(64,4,2), 256, 0, stream>>>(points2, f2t);
  k_knn<<<dim3(64,NCHUNK,2), 256, 0, stream>>>(xyz1, p2pp, kpd, kpi);
  k_knn_merge<<<128, 256, 0, stream>>>(kpd, kpi, kidx, kww);
  k_interp<<<8192, 256, 0, stream>>>(f2t, kidx, kww, Yi);
  k_gemm1<<<dim3(2,256), 256, 0, stream>>>(W0b, points1, Yi, C1b, psum, psq);
  k_stats_f<<<256, 256, 0, stream>>>(psum, psq, g0, be0, scale1, shift1);
  k_gemm2<<<dim3(2,256), 256, 0, stream>>>(W1b, C1b, scale1, shift1, C2b, psum, psq);
  k_stats_f<<<256, 256, 0, stream>>>(psum, psq, g1, be1, scale2, shift2);
  k_bn_out<<<dim3(256,4,2), 256, 0, stream>>>(C2b, scale2, shift2, (float*)d_out);
}